// Round 11
// baseline (224.898 us; speedup 1.0000x reference)
//
#include <hip/hip_runtime.h>
#include <math.h>

#define ND 3072
#define EDG 100000
#define MAXE 128
#define BSL (64*8 + 16)    // padded B k-slab stride (ushorts)

typedef __attribute__((ext_vector_type(8))) short short8;
typedef __attribute__((ext_vector_type(4))) float f32x4;

// ---------------- workspace layout (float offsets) ----------------
enum : size_t {
  OFF_FEATD = 0,                         // 3072*128
  OFF_FEATT = OFF_FEATD + 393216,
  OFF_WHD   = OFF_FEATT + 393216,        // 3072*16
  OFF_WHT   = OFF_WHD + 49152,
  OFF_S1D   = OFF_WHT + 49152,
  OFF_S2D   = OFF_S1D + 3072,
  OFF_S1T   = OFF_S2D + 3072,
  OFF_S2T   = OFF_S1T + 3072,
  OFF_HEADD = OFF_S2T + 3072,            // [2,2,3072,16]
  OFF_HEADT = OFF_HEADD + 196608,
  OFF_PGD   = OFF_HEADT + 196608,        // [2,3072,16]
  OFF_PGT   = OFF_PGD + 98304,
  OFF_F16D  = OFF_PGT + 98304,           // [3072,16]
  OFF_F16T  = OFF_F16D + 49152,
  OFF_AWS   = OFF_F16T + 49152,          // [16][128]
  OFF_W1D   = OFF_AWS + 2048,            // [16][64]
  OFF_W1T   = OFF_W1D + 1024,
  OFF_AOM   = OFF_W1T + 1024,            // [16]
  OFF_DOTSD = OFF_AOM + 16,              // [2][3072]
  OFF_DOTST = OFF_DOTSD + 6144,
  OFF_S2MD  = OFF_DOTST + 6144,          // uint-encoded max slots
  OFF_S2MT  = OFF_S2MD + 1,
  // weight splits [K/8][N][8] bf16 hi/lo
  OFF_W1DH  = ((OFF_S2MT + 4) & ~(size_t)3),
  OFF_W1DL  = OFF_W1DH + 262144,
  OFF_W1TH  = OFF_W1DL + 262144,
  OFF_W1TL  = OFF_W1TH + 327680,
  OFF_W2DH  = OFF_W1TL + 327680,
  OFF_W2DL  = OFF_W2DH + 65536,
  OFF_W2TH  = OFF_W2DL + 65536,
  OFF_W2TL  = OFF_W2TH + 65536,
  OFF_W3DH  = OFF_W2TL + 65536,
  OFF_W3DL  = OFF_W3DH + 16384,
  OFF_W3TH  = OFF_W3DL + 16384,
  OFF_W3TL  = OFF_W3TH + 16384,
  // input splits, row-major bf16 hi/lo
  OFF_XDH   = OFF_W3TL + 16384,
  OFF_XDL   = OFF_XDH + 1572864,
  OFF_XTH   = OFF_XDL + 1572864,
  OFF_XTL   = OFF_XTH + 1966080,
  // activation splits (row-major bf16 hi/lo); eidx/cnt overlay these later
  OFF_H1DH  = OFF_XTL + 1966080,
  OFF_H1DL  = OFF_H1DH + 786432,
  OFF_H1TH  = OFF_H1DL + 786432,
  OFF_H1TL  = OFF_H1TH + 786432,
  OFF_H2DH  = OFF_H1TL + 786432,
  OFF_H2DL  = OFF_H2DH + 393216,
  OFF_H2TH  = OFF_H2DL + 393216,
  OFF_H2TL  = OFF_H2TH + 393216,
  WS_GRAND  = OFF_H2TL + 393216
};

// ---------------- bf16 split helpers ----------------
__device__ __forceinline__ ushort f2bf(float f) {
  union { float f; unsigned u; } v; v.f = f;
  unsigned r = (v.u + 0x7fffu + ((v.u >> 16) & 1u)) >> 16;
  return (ushort)r;
}
__device__ __forceinline__ float bf2f(ushort h) {
  union { float f; unsigned u; } v; v.u = ((unsigned)h) << 16;
  return v.f;
}

// ---------------- mega prep: weight splits + input splits + small folds ----------------
__global__ __launch_bounds__(256) void prep_all(
    const float* __restrict__ w1d, const float* __restrict__ w1t,
    const float* __restrict__ w2d, const float* __restrict__ w2t,
    const float* __restrict__ w3d, const float* __restrict__ w3t,
    const float* __restrict__ xd,  const float* __restrict__ xt,
    const float* __restrict__ att_w, const float* __restrict__ dec_w1,
    const float* __restrict__ a_omega, float* __restrict__ ws)
{
  const int b = blockIdx.x, t = threadIdx.x;
  if (b < 736) {                         // [K][N] f32 -> [K/8][N][8] bf16 hi/lo
    const float* W; ushort* hi; ushort* lo; int nsh, base;
    if (b < 256)      { W=w1d; hi=(ushort*)(ws+OFF_W1DH); lo=(ushort*)(ws+OFF_W1DL); nsh=9; base=0; }
    else if (b < 576) { W=w1t; hi=(ushort*)(ws+OFF_W1TH); lo=(ushort*)(ws+OFF_W1TL); nsh=9; base=256; }
    else if (b < 640) { W=w2d; hi=(ushort*)(ws+OFF_W2DH); lo=(ushort*)(ws+OFF_W2DL); nsh=8; base=576; }
    else if (b < 704) { W=w2t; hi=(ushort*)(ws+OFF_W2TH); lo=(ushort*)(ws+OFF_W2TL); nsh=8; base=640; }
    else if (b < 720) { W=w3d; hi=(ushort*)(ws+OFF_W3DH); lo=(ushort*)(ws+OFF_W3DL); nsh=7; base=704; }
    else              { W=w3t; hi=(ushort*)(ws+OFF_W3TH); lo=(ushort*)(ws+OFF_W3TL); nsh=7; base=720; }
    const int u = (b - base)*256 + t;
    const int k8 = u >> nsh;
    const int n  = u & ((1 << nsh) - 1);
    __align__(16) ushort h8[8], l8[8];
    #pragma unroll
    for (int j2 = 0; j2 < 8; ++j2) {
      float x = W[(size_t)(k8*8 + j2) * (1 << nsh) + n];
      ushort h = f2bf(x);
      h8[j2] = h; l8[j2] = f2bf(x - bf2f(h));
    }
    *(uint4*)&hi[(size_t)u*8] = *(const uint4*)h8;
    *(uint4*)&lo[(size_t)u*8] = *(const uint4*)l8;
  } else if (b < 7648) {                 // row-major f32 -> row-major bf16 hi/lo
    const float* X; ushort* hi; ushort* lo; int base;
    if (b < 3808) { X=xd; hi=(ushort*)(ws+OFF_XDH); lo=(ushort*)(ws+OFF_XDL); base=736; }
    else          { X=xt; hi=(ushort*)(ws+OFF_XTH); lo=(ushort*)(ws+OFF_XTL); base=3808; }
    const size_t u = ((size_t)(b-base)*256 + t)*4;
    float4 v = *(const float4*)&X[u];
    ushort4 h, l;
    h.x=f2bf(v.x); l.x=f2bf(v.x-bf2f(h.x));
    h.y=f2bf(v.y); l.y=f2bf(v.y-bf2f(h.y));
    h.z=f2bf(v.z); l.z=f2bf(v.z-bf2f(h.z));
    h.w=f2bf(v.w); l.w=f2bf(v.w-bf2f(h.w));
    *(ushort4*)&hi[u] = h; *(ushort4*)&lo[u] = l;
  } else if (b == 7648) {                // aws + aom folds + s2max init
    float* aws = ws + OFF_AWS; float* aom = ws + OFF_AOM;
    for (int i = t; i < 2048; i += 256) {
      int d = i >> 7, o = i & 127;
      float sum = 0.f;
      #pragma unroll
      for (int tt = 0; tt < 8; ++tt) sum += att_w[(tt*16 + d)*128 + o];
      aws[i] = sum;
    }
    if (t < 16) {
      float sum = 0.f;
      #pragma unroll
      for (int tt = 0; tt < 8; ++tt) sum += a_omega[tt*16 + t];
      aom[t] = sum;
    }
    if (t == 0) {
      ((unsigned*)(ws + OFF_S2MD))[0] = 0u;   // encodes "most negative"
      ((unsigned*)(ws + OFF_S2MT))[0] = 0u;
    }
  } else {                               // dec_w1 folds
    float* W1d = ws + OFF_W1D; float* W1t = ws + OFF_W1T;
    for (int i = t; i < 1024; i += 256) {
      int d = i >> 6, o = i & 63;
      float sd = 0.f, st = 0.f;
      #pragma unroll
      for (int tt = 0; tt < 8; ++tt) {
        sd += dec_w1[(tt*16 + d)*64 + o];
        st += dec_w1[(128 + tt*16 + d)*64 + o];
      }
      W1d[i] = sd; W1t[i] = st;
    }
  }
}

// ---------------- split-bf16 MFMA GEMM, merged drug+target, BM-templated ----------------
// Named staging registers (no arrays, no lambda -> stays in VGPRs, rule #20);
// prefetch issued after LDS-write barrier so it flies under the MFMA cluster.
template<int BM, int EPI>
__global__ __launch_bounds__(256) void mfma_gemm2(
    const ushort* __restrict__ A0h, const ushort* __restrict__ A0l,
    const ushort* __restrict__ B0h, const ushort* __restrict__ B0l,
    const float* __restrict__ b0, float* __restrict__ C0f,
    ushort* __restrict__ C0h, ushort* __restrict__ C0l,
    const ushort* __restrict__ A1h, const ushort* __restrict__ A1l,
    const ushort* __restrict__ B1h, const ushort* __restrict__ B1l,
    const float* __restrict__ b1, float* __restrict__ C1f,
    ushort* __restrict__ C1h, ushort* __restrict__ C1l,
    int N, int K0, int K1)
{
  constexpr int ASLT = BM*8 + 16;        // padded A k-slab stride
  constexpr int NP   = 3072 / BM;        // row panels per half
  constexpr int AI   = BM / 32;          // per-thread A staging units (4 or 2)
  __shared__ __align__(16) ushort Ah[8*ASLT], Al[8*ASLT];
  __shared__ __align__(16) ushort Bh[8*BSL], Bl[8*BSL];
  const int t = threadIdx.x;
  const int lane = t & 63, w = t >> 6;
  const int wr = w >> 1, wc = w & 1;
  const int l15 = lane & 15, l4 = lane >> 4;

  // XCD-aware swizzle (total grid divisible by 8)
  const int id = blockIdx.y * gridDim.x + blockIdx.x;
  const int xcd = id & 7;
  const int j = id >> 3;
  const int bx = j % gridDim.x;
  const int by = (j / gridDim.x) * 8 + xcd;
  const int half = by >= NP;
  const int row0 = (half ? by - NP : by) * BM;
  const int col0 = bx << 6;
  const ushort* Ahi = half ? A1h : A0h; const ushort* Alo = half ? A1l : A0l;
  const ushort* Bhi = half ? B1h : B0h; const ushort* Blo = half ? B1l : B0l;
  const float* bias = half ? b1 : b0;
  float* Cf = half ? C1f : C0f;
  ushort* Chi = half ? C1h : C0h; ushort* Clo = half ? C1l : C0l;
  const int K = half ? K1 : K0;

  f32x4 acc[AI][2] = {};

  const int arow = t >> 3;        // 0..31
  const int akc  = t & 7;         // k-chunk 0..7
  const int bkc  = t >> 6;        // 0..3
  const int bcol = t & 63;

  uint4 sa0, sa1, sa2, sa3, sl0, sl1, sl2, sl3, sb0, sb1, sc0, sc1;

#define GLOAD(k0_) { \
    size_t g0 = (size_t)(row0 + arow) * K + (k0_) + (akc << 3); \
    sa0 = *(const uint4*)(Ahi + g0);                     sl0 = *(const uint4*)(Alo + g0); \
    sa1 = *(const uint4*)(Ahi + g0 + 32*(size_t)K);      sl1 = *(const uint4*)(Alo + g0 + 32*(size_t)K); \
    if (AI > 2) { \
      sa2 = *(const uint4*)(Ahi + g0 + 64*(size_t)K);    sl2 = *(const uint4*)(Alo + g0 + 64*(size_t)K); \
      sa3 = *(const uint4*)(Ahi + g0 + 96*(size_t)K);    sl3 = *(const uint4*)(Alo + g0 + 96*(size_t)K); \
    } \
    size_t gb0 = ((size_t)(((k0_) >> 3) + bkc    ) * N + col0 + bcol) << 3; \
    size_t gb1 = ((size_t)(((k0_) >> 3) + bkc + 4) * N + col0 + bcol) << 3; \
    sb0 = *(const uint4*)(Bhi + gb0); sc0 = *(const uint4*)(Blo + gb0); \
    sb1 = *(const uint4*)(Bhi + gb1); sc1 = *(const uint4*)(Blo + gb1); \
  }

#define LDSW() { \
    int ao = akc * ASLT + arow * 8; \
    *(uint4*)&Ah[ao      ] = sa0;  *(uint4*)&Al[ao      ] = sl0; \
    *(uint4*)&Ah[ao + 256] = sa1;  *(uint4*)&Al[ao + 256] = sl1; \
    if (AI > 2) { \
      *(uint4*)&Ah[ao + 512] = sa2;  *(uint4*)&Al[ao + 512] = sl2; \
      *(uint4*)&Ah[ao + 768] = sa3;  *(uint4*)&Al[ao + 768] = sl3; \
    } \
    int bo = bkc * BSL + bcol * 8; \
    *(uint4*)&Bh[bo        ] = sb0; *(uint4*)&Bl[bo        ] = sc0; \
    *(uint4*)&Bh[bo + 4*BSL] = sb1; *(uint4*)&Bl[bo + 4*BSL] = sc1; \
  }

  GLOAD(0);
  for (int k0 = 0; k0 < K; k0 += 64) {
    __syncthreads();
    LDSW();
    __syncthreads();
    if (k0 + 64 < K) GLOAD(k0 + 64);     // prefetch into named regs, flies under MFMA
    #pragma unroll
    for (int ks = 0; ks < 2; ++ks) {
      const int kch = (ks << 2) + l4;
      const int bbase = kch * BSL + ((wc << 5) + l15) * 8;
      short8 fb0 = *(const short8*)&Bh[bbase];
      short8 fb1 = *(const short8*)&Bh[bbase + 128];
      short8 gl0 = *(const short8*)&Bl[bbase];
      short8 gl1 = *(const short8*)&Bl[bbase + 128];
      #pragma unroll
      for (int m = 0; m < AI; ++m) {
        const int abase = kch * ASLT + (wr*(BM/2) + (m << 4) + l15) * 8;
        short8 fa = *(const short8*)&Ah[abase];
        short8 fl = *(const short8*)&Al[abase];
        acc[m][0] = __builtin_amdgcn_mfma_f32_16x16x32_bf16(fa, fb0, acc[m][0], 0, 0, 0);
        acc[m][0] = __builtin_amdgcn_mfma_f32_16x16x32_bf16(fa, gl0, acc[m][0], 0, 0, 0);
        acc[m][0] = __builtin_amdgcn_mfma_f32_16x16x32_bf16(fl, fb0, acc[m][0], 0, 0, 0);
        acc[m][1] = __builtin_amdgcn_mfma_f32_16x16x32_bf16(fa, fb1, acc[m][1], 0, 0, 0);
        acc[m][1] = __builtin_amdgcn_mfma_f32_16x16x32_bf16(fa, gl1, acc[m][1], 0, 0, 0);
        acc[m][1] = __builtin_amdgcn_mfma_f32_16x16x32_bf16(fl, fb1, acc[m][1], 0, 0, 0);
      }
    }
  }
#undef GLOAD
#undef LDSW

  // ---- epilogue: bias + relu; C/D layout col=lane&15, row=(lane>>4)*4+reg ----
  #pragma unroll
  for (int n = 0; n < 2; ++n) {
    int col = col0 + (wc << 5) + (n << 4) + l15;
    float bb = bias[col];
    #pragma unroll
    for (int m = 0; m < AI; ++m) {
      int rowb = row0 + wr*(BM/2) + (m << 4) + (l4 << 2);
      #pragma unroll
      for (int r = 0; r < 4; ++r) {
        float v = fmaxf(acc[m][n][r] + bb, 0.f);
        size_t d = (size_t)(rowb + r) * N + col;
        if (EPI == 0) {
          Cf[d] = v;
        } else {
          ushort h = f2bf(v);
          Chi[d] = h;
          Clo[d] = f2bf(v - bf2f(h));
        }
      }
    }
  }
}

// ---------------- wh = feats@gat_w; s1, s2; + deterministic global max(s2) ----------------
__global__ __launch_bounds__(256) void wh_kernel(const float* __restrict__ featD,
    const float* __restrict__ featT,
    const float* __restrict__ gw, const float* __restrict__ ga1, const float* __restrict__ ga2,
    float* __restrict__ ws)
{
  __shared__ float W[128*16];
  __shared__ float A1[16], A2[16];
  const int t = threadIdx.x;
  const int half = blockIdx.x >= 192;
  const float* feat = half ? featT : featD;
  float* wh = ws + (half ? OFF_WHT : OFF_WHD);
  float* s1 = ws + (half ? OFF_S1T : OFF_S1D);
  float* s2 = ws + (half ? OFF_S2T : OFF_S2D);
  unsigned* s2m = (unsigned*)(ws + (half ? OFF_S2MT : OFF_S2MD));
  const int bid = half ? blockIdx.x - 192 : blockIdx.x;
  for (int i = t; i < 2048; i += 256) W[i] = gw[i];
  if (t < 16) { A1[t] = ga1[t]; A2[t] = ga2[t]; }
  __syncthreads();
  const int n = (bid << 4) + (t >> 4);
  const int d = t & 15;
  const float* f = feat + (size_t)n * 128;
  float acc = 0.f;
  #pragma unroll 8
  for (int k = 0; k < 128; ++k) acc += f[k] * W[k*16 + d];
  wh[(size_t)n*16 + d] = acc;
  float v1 = acc * A1[d], v2 = acc * A2[d];
  #pragma unroll
  for (int off = 8; off; off >>= 1) { v1 += __shfl_xor(v1, off); v2 += __shfl_xor(v2, off); }
  if (d == 0) {
    s1[n] = v1; s2[n] = v2;
    unsigned u = __float_as_uint(v2);
    unsigned key = (u & 0x80000000u) ? ~u : (u | 0x80000000u);  // monotone encoding
    atomicMax(s2m, key);                                        // max: order-independent
  }
}

// ---------------- phase A: stream bias, compact edge indices (merged) ----------------
__global__ __launch_bounds__(256) void scan_kernel(const float* __restrict__ bias_d,
    const float* __restrict__ bias_t, float* __restrict__ ws)
{
  const int half = blockIdx.x >= 3072;
  const float* bias = half ? bias_t : bias_d;
  unsigned short* idx = (unsigned short*)(ws + (half ? OFF_H1TH : OFF_H1DH));
  int* cnts = (int*)(ws + (half ? OFF_H2TH : OFF_H2DH));
  const int bid = half ? blockIdx.x - 3072 : blockIdx.x;
  const int lane = threadIdx.x & 63;
  const int row = (bid << 2) + (threadIdx.x >> 6);
  const f32x4* brow = (const f32x4*)(bias + (size_t)row * ND);
  unsigned short* ei = idx + (size_t)row * MAXE;
  const unsigned long long ltmask = (1ull << lane) - 1ull;
  int cnt = 0;
  #pragma unroll 3
  for (int i = 0; i < ND/256; ++i) {
    const int j4 = lane + (i << 6);
    f32x4 b = __builtin_nontemporal_load(&brow[j4]);
    #pragma unroll
    for (int c = 0; c < 4; ++c) {
      float bv = b[c];
      bool e = bv > -1e8f;
      unsigned long long mask = __ballot(e);
      if (e) {
        int pos = cnt + __popcll(mask & ltmask);
        if (pos < MAXE) ei[pos] = (unsigned short)((j4 << 2) + c);
      }
      cnt += __popcll(mask);
    }
  }
  if (lane == 0) cnts[row] = cnt < MAXE ? cnt : MAXE;
}

// ---------------- phase B: softmax aggregation over compacted edges (merged) ----------------
__global__ __launch_bounds__(256) void acc_kernel(float* __restrict__ ws)
{
  const int half = blockIdx.x >= 3072;
  const unsigned short* idx = (const unsigned short*)(ws + (half ? OFF_H1TH : OFF_H1DH));
  const int* cnts = (const int*)(ws + (half ? OFF_H2TH : OFF_H2DH));
  const float* s1 = ws + (half ? OFF_S1T : OFF_S1D);
  const float* s2 = ws + (half ? OFF_S2T : OFF_S2D);
  const unsigned* s2mp = (const unsigned*)(ws + (half ? OFF_S2MT : OFF_S2MD));
  const float* wh = ws + (half ? OFF_WHT : OFF_WHD);
  float* head = ws + (half ? OFF_HEADT : OFF_HEADD);
  const int bid = half ? blockIdx.x - 3072 : blockIdx.x;
  const int lane = threadIdx.x & 63;
  const int row = (bid << 2) + (threadIdx.x >> 6);
  const int n = row % ND;
  const int eg = lane >> 4, d = lane & 15;
  const float s1v = s1[n];
  const unsigned k2 = *s2mp;
  const float s2mv = (k2 & 0x80000000u) ? __uint_as_float(k2 ^ 0x80000000u)
                                        : __uint_as_float(~k2);
  float mn = s1v + s2mv;
  mn = (mn >= 0.f) ? mn : 0.2f * mn;
  const unsigned short* ei = idx + (size_t)row * MAXE;
  const int cnt = cnts[row];
  float acc = 0.f, ss = 0.f;
  if (cnt > 0) {
    for (int slot = eg; slot < cnt; slot += 4) {
      int j = ei[slot];
      float x = s1v + s2[j];
      x = (x >= 0.f) ? x : 0.2f * x;
      float p = __expf(x - mn);
      ss += p;
      acc += p * wh[j*16 + d];
    }
  } else {
    for (int j = eg; j < ND; j += 4) {
      float x = s1v + s2[j];
      x = (x >= 0.f) ? x : 0.2f * x;
      float p = __expf(x - mn);
      ss += p;
      acc += p * wh[j*16 + d];
    }
  }
  acc += __shfl_xor(acc, 16); acc += __shfl_xor(acc, 32);
  ss  += __shfl_xor(ss, 16);  ss  += __shfl_xor(ss, 32);
  if (lane < 16) {
    float v = acc / ss;
    head[(size_t)row * 16 + lane] = (v > 0.f) ? v : expm1f(v);
  }
}

// ---------------- semantic attention per (g,n) (merged) ----------------
__global__ __launch_bounds__(256) void sem_kernel(const float* __restrict__ att_b,
    const float* __restrict__ att_u, float* __restrict__ ws)
{
  __shared__ float AWS[2048];
  __shared__ float AB[128], AU[128], AOM[16];
  __shared__ float hsh[2][2][16];
  __shared__ float wred[4][2];
  const int half = blockIdx.x >= 3072;
  const float* head = ws + (half ? OFF_HEADT : OFF_HEADD);
  float* pg = ws + (half ? OFF_PGT : OFF_PGD);
  float* dots = ws + (half ? OFF_DOTST : OFF_DOTSD);
  const float* aws = ws + OFF_AWS;
  const float* aom = ws + OFF_AOM;
  const int bid = half ? blockIdx.x - 3072 : blockIdx.x;
  const int t = threadIdx.x;
  for (int i = t; i < 2048; i += 256) AWS[i] = aws[i];
  if (t < 128) { AB[t] = att_b[t]; AU[t] = att_u[t]; }
  if (t < 16) AOM[t] = aom[t];
  const int grp = t >> 7, o = t & 127;
  const int gn = (bid << 1) + grp;
  const int g = gn / ND, n = gn % ND;
  if (o < 32) {
    int r = o >> 4, d = o & 15;
    hsh[grp][r][d] = head[((size_t)(g*2 + r) * ND + n) * 16 + d];
  }
  __syncthreads();
  #pragma unroll
  for (int r = 0; r < 2; ++r) {
    float a = AB[o];
    #pragma unroll
    for (int d = 0; d < 16; ++d) a += hsh[grp][r][d] * AWS[d*128 + o];
    float v = tanhf(a) * AU[o];
    #pragma unroll
    for (int off = 32; off; off >>= 1) v += __shfl_xor(v, off);
    if ((t & 63) == 0) wred[t >> 6][r] = v;
  }
  __syncthreads();
  float t0 = wred[grp*2][0] + wred[grp*2 + 1][0];
  float t1 = wred[grp*2][1] + wred[grp*2 + 1][1];
  float mx = fmaxf(t0, t1);
  float e0 = __expf(t0 - mx), e1 = __expf(t1 - mx);
  float inv = 1.f / (e0 + e1);
  float a0 = e0 * inv, a1 = e1 * inv;
  if (o < 16) {
    float pv = a0 * hsh[grp][0][o] + a1 * hsh[grp][1][o];
    pg[((size_t)g * ND + n) * 16 + o] = pv;
    float contrib = pv * AOM[o];
    #pragma unroll
    for (int off = 8; off; off >>= 1) contrib += __shfl_xor(contrib, off);
    if (o == 0) dots[(size_t)g * ND + n] = contrib;
  }
}

// ---------------- graph softmax + combine; gsum computed inline (deterministic) ----------------
__global__ __launch_bounds__(256) void finalize_kernel(float* __restrict__ ws)
{
  const int half = blockIdx.x >= 192;
  const float* pg = ws + (half ? OFF_PGT : OFF_PGD);
  const float* dots = ws + (half ? OFF_DOTST : OFF_DOTSD);
  float* f16 = ws + (half ? OFF_F16T : OFF_F16D);
  const int bid = half ? blockIdx.x - 192 : blockIdx.x;
  const int t = threadIdx.x;
  float v0 = 0.f, v1 = 0.f;
  for (int i = t; i < ND; i += 256) { v0 += dots[i]; v1 += dots[ND + i]; }
  #pragma unroll
  for (int off = 32; off; off >>= 1) { v0 += __shfl_xor(v0, off); v1 += __shfl_xor(v1, off); }
  __shared__ float red[4][2];
  if ((t & 63) == 0) { red[t >> 6][0] = v0; red[t >> 6][1] = v1; }
  __syncthreads();
  float g0 = (red[0][0] + red[1][0] + red[2][0] + red[3][0]) * (1.f/ND);
  float g1 = (red[0][1] + red[1][1] + red[2][1] + red[3][1]) * (1.f/ND);
  float mx = fmaxf(g0, g1);
  float e0 = __expf(g0 - mx), e1 = __expf(g1 - mx);
  float w0 = e0 / (e0 + e1), w1 = e1 / (e0 + e1);
  int i = bid * 256 + t;
  if (i < ND*16) f16[i] = w0 * pg[i] + w1 * pg[ND*16 + i];
}

// ---------------- decoder ----------------
__global__ __launch_bounds__(256) void dec_kernel(const int* __restrict__ ei,
    const float* __restrict__ ws, const float* __restrict__ b1,
    const float* __restrict__ w2, const float* __restrict__ b2,
    float* __restrict__ out)
{
  __shared__ float WdT[64][16], WtT[64][16];
  __shared__ float B1[64], W2s[64];
  const float* f16d = ws + OFF_F16D;
  const float* f16t = ws + OFF_F16T;
  const float* W1d = ws + OFF_W1D;
  const float* W1t = ws + OFF_W1T;
  const int t = threadIdx.x;
  for (int i = t; i < 1024; i += 256) {
    int d = i >> 6, o = i & 63;
    WdT[o][d] = W1d[i];
    WtT[o][d] = W1t[i];
  }
  if (t < 64) { B1[t] = b1[t]; W2s[t] = w2[t]; }
  __syncthreads();
  const int e = blockIdx.x * 256 + t;
  if (e >= EDG) return;
  const int i0 = ei[e], i1 = ei[EDG + e];
  const float4* pd = (const float4*)(f16d + (size_t)i0 * 16);
  const float4* pt = (const float4*)(f16t + (size_t)i1 * 16);
  float4 d0 = pd[0], d1 = pd[1], d2 = pd[2], d3 = pd[3];
  float4 e0 = pt[0], e1 = pt[1], e2 = pt[2], e3 = pt[3];
  float outv = b2[0];
  #pragma unroll 4
  for (int o = 0; o < 64; ++o) {
    const float4* wd = (const float4*)&WdT[o][0];
    const float4* wt = (const float4*)&WtT[o][0];
    float4 wd0 = wd[0], wd1 = wd[1], wd2 = wd[2], wd3 = wd[3];
    float4 wt0 = wt[0], wt1 = wt[1], wt2 = wt[2], wt3 = wt[3];
    float a = B1[o];
    a += d0.x*wd0.x + d0.y*wd0.y + d0.z*wd0.z + d0.w*wd0.w;
    a += d1.x*wd1.x + d1.y*wd1.y + d1.z*wd1.z + d1.w*wd1.w;
    a += d2.x*wd2.x + d2.y*wd2.y + d2.z*wd2.z + d2.w*wd2.w;
    a += d3.x*wd3.x + d3.y*wd3.y + d3.z*wd3.z + d3.w*wd3.w;
    a += e0.x*wt0.x + e0.y*wt0.y + e0.z*wt0.z + e0.w*wt0.w;
    a += e1.x*wt1.x + e1.y*wt1.y + e1.z*wt1.z + e1.w*wt1.w;
    a += e2.x*wt2.x + e2.y*wt2.y + e2.z*wt2.z + e2.w*wt2.w;
    a += e3.x*wt3.x + e3.y*wt3.y + e3.z*wt3.z + e3.w*wt3.w;
    a = fmaxf(a, 0.f);
    outv += a * W2s[o];
  }
  out[e] = 1.f / (1.f + __expf(-outv));
}

// ---------------- launch ----------------
extern "C" void kernel_launch(void* const* d_in, const int* in_sizes, int n_in,
                              void* d_out, int out_size, void* d_ws, size_t ws_size,
                              hipStream_t stream)
{
  const float* x_drug   = (const float*)d_in[0];
  const float* x_target = (const float*)d_in[1];
  const float* bias_d   = (const float*)d_in[2];
  const float* bias_t   = (const float*)d_in[3];
  const int*   ei       = (const int*)d_in[4];
  const float* dnn_w1 = (const float*)d_in[5];  const float* dnn_b1 = (const float*)d_in[6];
  const float* dnn_w2 = (const float*)d_in[7];  const float* dnn_b2 = (const float*)d_in[8];
  const float* dnn_w3 = (const float*)d_in[9];  const float* dnn_b3 = (const float*)d_in[10];
  const float* tnn_w1 = (const float*)d_in[11]; const float* tnn_b1 = (const float*)d_in[12];
  const float* tnn_w2 = (const float*)d_in[13]; const float* tnn_b2 = (const float*)d_in[14];
  const float* tnn_w3 = (const float*)d_in[15]; const float* tnn_b3 = (const float*)d_in[16];
  const float* gat_w  = (const float*)d_in[17];
  const float* gat_a1 = (const float*)d_in[18];
  const float* gat_a2 = (const float*)d_in[19];
  const float* att_w  = (const float*)d_in[20];
  const float* att_b  = (const float*)d_in[21];
  const float* att_u  = (const float*)d_in[22];
  const float* a_omega= (const float*)d_in[23];
  const float* dec_w1 = (const float*)d_in[24]; const float* dec_b1 = (const float*)d_in[25];
  const float* dec_w2 = (const float*)d_in[26]; const float* dec_b2 = (const float*)d_in[27];
  float* out = (float*)d_out;
  float* ws = (float*)d_ws;

  ushort* w1dh = (ushort*)(ws + OFF_W1DH); ushort* w1dl = (ushort*)(ws + OFF_W1DL);
  ushort* w1th = (ushort*)(ws + OFF_W1TH); ushort* w1tl = (ushort*)(ws + OFF_W1TL);
  ushort* w2dh = (ushort*)(ws + OFF_W2DH); ushort* w2dl = (ushort*)(ws + OFF_W2DL);
  ushort* w2th = (ushort*)(ws + OFF_W2TH); ushort* w2tl = (ushort*)(ws + OFF_W2TL);
  ushort* w3dh = (ushort*)(ws + OFF_W3DH); ushort* w3dl = (ushort*)(ws + OFF_W3DL);
  ushort* w3th = (ushort*)(ws + OFF_W3TH); ushort* w3tl = (ushort*)(ws + OFF_W3TL);
  ushort* xdh  = (ushort*)(ws + OFF_XDH);  ushort* xdl  = (ushort*)(ws + OFF_XDL);
  ushort* xth  = (ushort*)(ws + OFF_XTH);  ushort* xtl  = (ushort*)(ws + OFF_XTL);
  ushort* h1dh = (ushort*)(ws + OFF_H1DH); ushort* h1dl = (ushort*)(ws + OFF_H1DL);
  ushort* h1th = (ushort*)(ws + OFF_H1TH); ushort* h1tl = (ushort*)(ws + OFF_H1TL);
  ushort* h2dh = (ushort*)(ws + OFF_H2DH); ushort* h2dl = (ushort*)(ws + OFF_H2DL);
  ushort* h2th = (ushort*)(ws + OFF_H2TH); ushort* h2tl = (ushort*)(ws + OFF_H2TL);
  float* featD = ws + OFF_FEATD;
  float* featT = ws + OFF_FEATT;

  prep_all<<<7650, 256, 0, stream>>>(dnn_w1, tnn_w1, dnn_w2, tnn_w2, dnn_w3, tnn_w3,
      x_drug, x_target, att_w, dec_w1, a_omega, ws);

  // L1: drug K=1024, target K=1280 (N=512), BM=128 -> grid (8,48)=384 blocks
  mfma_gemm2<128,1><<<dim3(8,48), 256, 0, stream>>>(
      xdh, xdl, w1dh, w1dl, dnn_b1, nullptr, h1dh, h1dl,
      xth, xtl, w1th, w1tl, tnn_b1, nullptr, h1th, h1tl, 512, 1024, 1280);
  // L2: K=512, N=256, BM=64 -> grid (4,96)=384 blocks
  mfma_gemm2<64,1><<<dim3(4,96), 256, 0, stream>>>(
      h1dh, h1dl, w2dh, w2dl, dnn_b2, nullptr, h2dh, h2dl,
      h1th, h1tl, w2th, w2tl, tnn_b2, nullptr, h2th, h2tl, 256, 512, 512);
  // L3: K=256, N=128, BM=64 -> grid (2,96)=192 blocks, f32 out
  mfma_gemm2<64,0><<<dim3(2,96), 256, 0, stream>>>(
      h2dh, h2dl, w3dh, w3dl, dnn_b3, featD, nullptr, nullptr,
      h2th, h2tl, w3th, w3tl, tnn_b3, featT, nullptr, nullptr, 128, 256, 256);

  wh_kernel<<<384, 256, 0, stream>>>(featD, featT, gat_w, gat_a1, gat_a2, ws);

  scan_kernel<<<6144, 256, 0, stream>>>(bias_d, bias_t, ws);
  acc_kernel<<<6144, 256, 0, stream>>>(ws);

  sem_kernel<<<6144, 256, 0, stream>>>(att_b, att_u, ws);
  finalize_kernel<<<384, 256, 0, stream>>>(ws);

  dec_kernel<<<(EDG + 255) / 256, 256, 0, stream>>>(ei, ws, dec_b1, dec_w2, dec_b2, out);
}

// Round 12
// 211.959 us; speedup vs baseline: 1.0610x; 1.0610x over previous
//
#include <hip/hip_runtime.h>
#include <math.h>

#define ND 3072
#define EDG 100000
#define MAXE 128
#define BSL (64*8 + 16)    // padded B k-slab stride (ushorts)

typedef __attribute__((ext_vector_type(8))) short short8;
typedef __attribute__((ext_vector_type(4))) float f32x4;

// ---------------- workspace layout (float offsets) ----------------
enum : size_t {
  OFF_FEATD = 0,                         // 3072*128
  OFF_FEATT = OFF_FEATD + 393216,
  OFF_WHD   = OFF_FEATT + 393216,        // 3072*16
  OFF_WHT   = OFF_WHD + 49152,
  OFF_S1D   = OFF_WHT + 49152,
  OFF_S2D   = OFF_S1D + 3072,
  OFF_S1T   = OFF_S2D + 3072,
  OFF_S2T   = OFF_S1T + 3072,
  OFF_HEADD = OFF_S2T + 3072,            // [2,2,3072,16]
  OFF_HEADT = OFF_HEADD + 196608,
  OFF_PGD   = OFF_HEADT + 196608,        // [2,3072,16]
  OFF_PGT   = OFF_PGD + 98304,
  OFF_F16D  = OFF_PGT + 98304,           // [3072,16]
  OFF_F16T  = OFF_F16D + 49152,
  OFF_AWS   = OFF_F16T + 49152,          // [16][128]
  OFF_W1D   = OFF_AWS + 2048,            // [16][64]
  OFF_W1T   = OFF_W1D + 1024,
  OFF_AOM   = OFF_W1T + 1024,            // [16]
  OFF_DOTSD = OFF_AOM + 16,              // [2][3072]
  OFF_DOTST = OFF_DOTSD + 6144,
  OFF_S2MD  = OFF_DOTST + 6144,          // uint-encoded max slots
  OFF_S2MT  = OFF_S2MD + 1,
  // weight splits [K/8][N][8] bf16 hi/lo
  OFF_W1DH  = ((OFF_S2MT + 4) & ~(size_t)3),
  OFF_W1DL  = OFF_W1DH + 262144,
  OFF_W1TH  = OFF_W1DL + 262144,
  OFF_W1TL  = OFF_W1TH + 327680,
  OFF_W2DH  = OFF_W1TL + 327680,
  OFF_W2DL  = OFF_W2DH + 65536,
  OFF_W2TH  = OFF_W2DL + 65536,
  OFF_W2TL  = OFF_W2TH + 65536,
  OFF_W3DH  = OFF_W2TL + 65536,
  OFF_W3DL  = OFF_W3DH + 16384,
  OFF_W3TH  = OFF_W3DL + 16384,
  OFF_W3TL  = OFF_W3TH + 16384,
  // input splits, row-major bf16 hi/lo
  OFF_XDH   = OFF_W3TL + 16384,
  OFF_XDL   = OFF_XDH + 1572864,
  OFF_XTH   = OFF_XDL + 1572864,
  OFF_XTL   = OFF_XTH + 1966080,
  // activation splits (row-major bf16 hi/lo)
  OFF_H1DH  = OFF_XTL + 1966080,
  OFF_H1DL  = OFF_H1DH + 786432,
  OFF_H1TH  = OFF_H1DL + 786432,
  OFF_H1TL  = OFF_H1TH + 786432,
  OFF_H2DH  = OFF_H1TL + 786432,
  OFF_H2DL  = OFF_H2DH + 393216,
  OFF_H2TH  = OFF_H2DL + 393216,
  OFF_H2TL  = OFF_H2TH + 393216,
  WS_GRAND  = OFF_H2TL + 393216
};

// ---------------- bf16 split helpers ----------------
__device__ __forceinline__ ushort f2bf(float f) {
  union { float f; unsigned u; } v; v.f = f;
  unsigned r = (v.u + 0x7fffu + ((v.u >> 16) & 1u)) >> 16;
  return (ushort)r;
}
__device__ __forceinline__ float bf2f(ushort h) {
  union { float f; unsigned u; } v; v.u = ((unsigned)h) << 16;
  return v.f;
}

// ---------------- mega prep: weight splits + input splits + small folds ----------------
__global__ __launch_bounds__(256) void prep_all(
    const float* __restrict__ w1d, const float* __restrict__ w1t,
    const float* __restrict__ w2d, const float* __restrict__ w2t,
    const float* __restrict__ w3d, const float* __restrict__ w3t,
    const float* __restrict__ xd,  const float* __restrict__ xt,
    const float* __restrict__ att_w, const float* __restrict__ dec_w1,
    const float* __restrict__ a_omega, float* __restrict__ ws)
{
  const int b = blockIdx.x, t = threadIdx.x;
  if (b < 736) {                         // [K][N] f32 -> [K/8][N][8] bf16 hi/lo
    const float* W; ushort* hi; ushort* lo; int nsh, base;
    if (b < 256)      { W=w1d; hi=(ushort*)(ws+OFF_W1DH); lo=(ushort*)(ws+OFF_W1DL); nsh=9; base=0; }
    else if (b < 576) { W=w1t; hi=(ushort*)(ws+OFF_W1TH); lo=(ushort*)(ws+OFF_W1TL); nsh=9; base=256; }
    else if (b < 640) { W=w2d; hi=(ushort*)(ws+OFF_W2DH); lo=(ushort*)(ws+OFF_W2DL); nsh=8; base=576; }
    else if (b < 704) { W=w2t; hi=(ushort*)(ws+OFF_W2TH); lo=(ushort*)(ws+OFF_W2TL); nsh=8; base=640; }
    else if (b < 720) { W=w3d; hi=(ushort*)(ws+OFF_W3DH); lo=(ushort*)(ws+OFF_W3DL); nsh=7; base=704; }
    else              { W=w3t; hi=(ushort*)(ws+OFF_W3TH); lo=(ushort*)(ws+OFF_W3TL); nsh=7; base=720; }
    const int u = (b - base)*256 + t;
    const int k8 = u >> nsh;
    const int n  = u & ((1 << nsh) - 1);
    __align__(16) ushort h8[8], l8[8];
    #pragma unroll
    for (int j2 = 0; j2 < 8; ++j2) {
      float x = W[(size_t)(k8*8 + j2) * (1 << nsh) + n];
      ushort h = f2bf(x);
      h8[j2] = h; l8[j2] = f2bf(x - bf2f(h));
    }
    *(uint4*)&hi[(size_t)u*8] = *(const uint4*)h8;
    *(uint4*)&lo[(size_t)u*8] = *(const uint4*)l8;
  } else if (b < 7648) {                 // row-major f32 -> row-major bf16 hi/lo
    const float* X; ushort* hi; ushort* lo; int base;
    if (b < 3808) { X=xd; hi=(ushort*)(ws+OFF_XDH); lo=(ushort*)(ws+OFF_XDL); base=736; }
    else          { X=xt; hi=(ushort*)(ws+OFF_XTH); lo=(ushort*)(ws+OFF_XTL); base=3808; }
    const size_t u = ((size_t)(b-base)*256 + t)*4;
    float4 v = *(const float4*)&X[u];
    ushort4 h, l;
    h.x=f2bf(v.x); l.x=f2bf(v.x-bf2f(h.x));
    h.y=f2bf(v.y); l.y=f2bf(v.y-bf2f(h.y));
    h.z=f2bf(v.z); l.z=f2bf(v.z-bf2f(h.z));
    h.w=f2bf(v.w); l.w=f2bf(v.w-bf2f(h.w));
    *(ushort4*)&hi[u] = h; *(ushort4*)&lo[u] = l;
  } else if (b == 7648) {                // aws + aom folds + s2max init
    float* aws = ws + OFF_AWS; float* aom = ws + OFF_AOM;
    for (int i = t; i < 2048; i += 256) {
      int d = i >> 7, o = i & 127;
      float sum = 0.f;
      #pragma unroll
      for (int tt = 0; tt < 8; ++tt) sum += att_w[(tt*16 + d)*128 + o];
      aws[i] = sum;
    }
    if (t < 16) {
      float sum = 0.f;
      #pragma unroll
      for (int tt = 0; tt < 8; ++tt) sum += a_omega[tt*16 + t];
      aom[t] = sum;
    }
    if (t == 0) {
      ((unsigned*)(ws + OFF_S2MD))[0] = 0u;   // encodes "most negative"
      ((unsigned*)(ws + OFF_S2MT))[0] = 0u;
    }
  } else {                               // dec_w1 folds
    float* W1d = ws + OFF_W1D; float* W1t = ws + OFF_W1T;
    for (int i = t; i < 1024; i += 256) {
      int d = i >> 6, o = i & 63;
      float sd = 0.f, st = 0.f;
      #pragma unroll
      for (int tt = 0; tt < 8; ++tt) {
        sd += dec_w1[(tt*16 + d)*64 + o];
        st += dec_w1[(128 + tt*16 + d)*64 + o];
      }
      W1d[i] = sd; W1t[i] = st;
    }
  }
}

// ---------------- split-bf16 MFMA GEMM, merged drug+target, BM-templated ----------------
template<int BM, int EPI>
__global__ __launch_bounds__(256) void mfma_gemm2(
    const ushort* __restrict__ A0h, const ushort* __restrict__ A0l,
    const ushort* __restrict__ B0h, const ushort* __restrict__ B0l,
    const float* __restrict__ b0, float* __restrict__ C0f,
    ushort* __restrict__ C0h, ushort* __restrict__ C0l,
    const ushort* __restrict__ A1h, const ushort* __restrict__ A1l,
    const ushort* __restrict__ B1h, const ushort* __restrict__ B1l,
    const float* __restrict__ b1, float* __restrict__ C1f,
    ushort* __restrict__ C1h, ushort* __restrict__ C1l,
    int N, int K0, int K1)
{
  constexpr int ASLT = BM*8 + 16;        // padded A k-slab stride
  constexpr int NP   = 3072 / BM;        // row panels per half
  constexpr int AI   = BM / 32;          // per-thread A staging units (4 or 2)
  __shared__ __align__(16) ushort Ah[8*ASLT], Al[8*ASLT];
  __shared__ __align__(16) ushort Bh[8*BSL], Bl[8*BSL];
  const int t = threadIdx.x;
  const int lane = t & 63, w = t >> 6;
  const int wr = w >> 1, wc = w & 1;
  const int l15 = lane & 15, l4 = lane >> 4;

  // XCD-aware swizzle (total grid divisible by 8)
  const int id = blockIdx.y * gridDim.x + blockIdx.x;
  const int xcd = id & 7;
  const int j = id >> 3;
  const int bx = j % gridDim.x;
  const int by = (j / gridDim.x) * 8 + xcd;
  const int half = by >= NP;
  const int row0 = (half ? by - NP : by) * BM;
  const int col0 = bx << 6;
  const ushort* Ahi = half ? A1h : A0h; const ushort* Alo = half ? A1l : A0l;
  const ushort* Bhi = half ? B1h : B0h; const ushort* Blo = half ? B1l : B0l;
  const float* bias = half ? b1 : b0;
  float* Cf = half ? C1f : C0f;
  ushort* Chi = half ? C1h : C0h; ushort* Clo = half ? C1l : C0l;
  const int K = half ? K1 : K0;

  f32x4 acc[AI][2] = {};

  const int arow = t >> 3;        // 0..31
  const int akc  = t & 7;         // k-chunk 0..7
  const int bkc  = t >> 6;        // 0..3
  const int bcol = t & 63;

  uint4 sa0, sa1, sa2, sa3, sl0, sl1, sl2, sl3, sb0, sb1, sc0, sc1;

#define GLOAD(k0_) { \
    size_t g0 = (size_t)(row0 + arow) * K + (k0_) + (akc << 3); \
    sa0 = *(const uint4*)(Ahi + g0);                     sl0 = *(const uint4*)(Alo + g0); \
    sa1 = *(const uint4*)(Ahi + g0 + 32*(size_t)K);      sl1 = *(const uint4*)(Alo + g0 + 32*(size_t)K); \
    if (AI > 2) { \
      sa2 = *(const uint4*)(Ahi + g0 + 64*(size_t)K);    sl2 = *(const uint4*)(Alo + g0 + 64*(size_t)K); \
      sa3 = *(const uint4*)(Ahi + g0 + 96*(size_t)K);    sl3 = *(const uint4*)(Alo + g0 + 96*(size_t)K); \
    } \
    size_t gb0 = ((size_t)(((k0_) >> 3) + bkc    ) * N + col0 + bcol) << 3; \
    size_t gb1 = ((size_t)(((k0_) >> 3) + bkc + 4) * N + col0 + bcol) << 3; \
    sb0 = *(const uint4*)(Bhi + gb0); sc0 = *(const uint4*)(Blo + gb0); \
    sb1 = *(const uint4*)(Bhi + gb1); sc1 = *(const uint4*)(Blo + gb1); \
  }

#define LDSW() { \
    int ao = akc * ASLT + arow * 8; \
    *(uint4*)&Ah[ao      ] = sa0;  *(uint4*)&Al[ao      ] = sl0; \
    *(uint4*)&Ah[ao + 256] = sa1;  *(uint4*)&Al[ao + 256] = sl1; \
    if (AI > 2) { \
      *(uint4*)&Ah[ao + 512] = sa2;  *(uint4*)&Al[ao + 512] = sl2; \
      *(uint4*)&Ah[ao + 768] = sa3;  *(uint4*)&Al[ao + 768] = sl3; \
    } \
    int bo = bkc * BSL + bcol * 8; \
    *(uint4*)&Bh[bo        ] = sb0; *(uint4*)&Bl[bo        ] = sc0; \
    *(uint4*)&Bh[bo + 4*BSL] = sb1; *(uint4*)&Bl[bo + 4*BSL] = sc1; \
  }

  GLOAD(0);
  for (int k0 = 0; k0 < K; k0 += 64) {
    __syncthreads();
    LDSW();
    __syncthreads();
    if (k0 + 64 < K) GLOAD(k0 + 64);     // prefetch into named regs, flies under MFMA
    #pragma unroll
    for (int ks = 0; ks < 2; ++ks) {
      const int kch = (ks << 2) + l4;
      const int bbase = kch * BSL + ((wc << 5) + l15) * 8;
      short8 fb0 = *(const short8*)&Bh[bbase];
      short8 fb1 = *(const short8*)&Bh[bbase + 128];
      short8 gl0 = *(const short8*)&Bl[bbase];
      short8 gl1 = *(const short8*)&Bl[bbase + 128];
      #pragma unroll
      for (int m = 0; m < AI; ++m) {
        const int abase = kch * ASLT + (wr*(BM/2) + (m << 4) + l15) * 8;
        short8 fa = *(const short8*)&Ah[abase];
        short8 fl = *(const short8*)&Al[abase];
        acc[m][0] = __builtin_amdgcn_mfma_f32_16x16x32_bf16(fa, fb0, acc[m][0], 0, 0, 0);
        acc[m][0] = __builtin_amdgcn_mfma_f32_16x16x32_bf16(fa, gl0, acc[m][0], 0, 0, 0);
        acc[m][0] = __builtin_amdgcn_mfma_f32_16x16x32_bf16(fl, fb0, acc[m][0], 0, 0, 0);
        acc[m][1] = __builtin_amdgcn_mfma_f32_16x16x32_bf16(fa, fb1, acc[m][1], 0, 0, 0);
        acc[m][1] = __builtin_amdgcn_mfma_f32_16x16x32_bf16(fa, gl1, acc[m][1], 0, 0, 0);
        acc[m][1] = __builtin_amdgcn_mfma_f32_16x16x32_bf16(fl, fb1, acc[m][1], 0, 0, 0);
      }
    }
  }
#undef GLOAD
#undef LDSW

  // ---- epilogue: bias + relu; C/D layout col=lane&15, row=(lane>>4)*4+reg ----
  #pragma unroll
  for (int n = 0; n < 2; ++n) {
    int col = col0 + (wc << 5) + (n << 4) + l15;
    float bb = bias[col];
    #pragma unroll
    for (int m = 0; m < AI; ++m) {
      int rowb = row0 + wr*(BM/2) + (m << 4) + (l4 << 2);
      #pragma unroll
      for (int r = 0; r < 4; ++r) {
        float v = fmaxf(acc[m][n][r] + bb, 0.f);
        size_t d = (size_t)(rowb + r) * N + col;
        if (EPI == 0) {
          Cf[d] = v;
        } else {
          ushort h = f2bf(v);
          Chi[d] = h;
          Clo[d] = f2bf(v - bf2f(h));
        }
      }
    }
  }
}

// ---------------- wh = feats@gat_w; s1, s2; + deterministic global max(s2) ----------------
__global__ __launch_bounds__(256) void wh_kernel(const float* __restrict__ featD,
    const float* __restrict__ featT,
    const float* __restrict__ gw, const float* __restrict__ ga1, const float* __restrict__ ga2,
    float* __restrict__ ws)
{
  __shared__ float W[128*16];
  __shared__ float A1[16], A2[16];
  const int t = threadIdx.x;
  const int half = blockIdx.x >= 192;
  const float* feat = half ? featT : featD;
  float* wh = ws + (half ? OFF_WHT : OFF_WHD);
  float* s1 = ws + (half ? OFF_S1T : OFF_S1D);
  float* s2 = ws + (half ? OFF_S2T : OFF_S2D);
  unsigned* s2m = (unsigned*)(ws + (half ? OFF_S2MT : OFF_S2MD));
  const int bid = half ? blockIdx.x - 192 : blockIdx.x;
  for (int i = t; i < 2048; i += 256) W[i] = gw[i];
  if (t < 16) { A1[t] = ga1[t]; A2[t] = ga2[t]; }
  __syncthreads();
  const int n = (bid << 4) + (t >> 4);
  const int d = t & 15;
  const float* f = feat + (size_t)n * 128;
  float acc = 0.f;
  #pragma unroll 8
  for (int k = 0; k < 128; ++k) acc += f[k] * W[k*16 + d];
  wh[(size_t)n*16 + d] = acc;
  float v1 = acc * A1[d], v2 = acc * A2[d];
  #pragma unroll
  for (int off = 8; off; off >>= 1) { v1 += __shfl_xor(v1, off); v2 += __shfl_xor(v2, off); }
  if (d == 0) {
    s1[n] = v1; s2[n] = v2;
    unsigned u = __float_as_uint(v2);
    unsigned key = (u & 0x80000000u) ? ~u : (u | 0x80000000u);  // monotone encoding
    atomicMax(s2m, key);                                        // max: order-independent
  }
}

// ---------------- fused: stream bias -> LDS edge compaction -> dense softmax gather ----------------
// one wave per (g,r,n) row; per-wave LDS slice; no __syncthreads (wave-local data).
__global__ __launch_bounds__(256) void scanacc_kernel(const float* __restrict__ bias_d,
    const float* __restrict__ bias_t, float* __restrict__ ws)
{
  __shared__ ushort eidx[4][MAXE];
  const int half = blockIdx.x >= 3072;
  const float* bias = half ? bias_t : bias_d;
  const float* s1 = ws + (half ? OFF_S1T : OFF_S1D);
  const float* s2 = ws + (half ? OFF_S2T : OFF_S2D);
  const unsigned* s2mp = (const unsigned*)(ws + (half ? OFF_S2MT : OFF_S2MD));
  const float* wh = ws + (half ? OFF_WHT : OFF_WHD);
  float* head = ws + (half ? OFF_HEADT : OFF_HEADD);
  const int bid = half ? blockIdx.x - 3072 : blockIdx.x;
  const int lane = threadIdx.x & 63;
  const int wv = threadIdx.x >> 6;
  const int row = (bid << 2) + wv;                 // (g*2+r)*ND + n
  const int n = row % ND;
  const f32x4* brow = (const f32x4*)(bias + (size_t)row * ND);
  ushort* ei = &eidx[wv][0];
  const unsigned long long ltmask = (1ull << lane) - 1ull;

  // ---- phase A: compact edge column indices into LDS ----
  int cnt = 0;
  #pragma unroll 3
  for (int i = 0; i < ND/256; ++i) {
    const int j4 = lane + (i << 6);
    f32x4 b = __builtin_nontemporal_load(&brow[j4]);
    #pragma unroll
    for (int c = 0; c < 4; ++c) {
      bool e = b[c] > -1e8f;
      unsigned long long mask = __ballot(e);
      if (e) {
        int pos = cnt + __popcll(mask & ltmask);
        if (pos < MAXE) ei[pos] = (unsigned short)((j4 << 2) + c);
      }
      cnt += __popcll(mask);             // wave-uniform
    }
  }
  if (cnt > MAXE) cnt = MAXE;

  // ---- phase B: dense softmax-weighted aggregation from LDS list ----
  const int eg = lane >> 4, d = lane & 15;
  const float s1v = s1[n];
  const unsigned k2 = *s2mp;
  const float s2mv = (k2 & 0x80000000u) ? __uint_as_float(k2 ^ 0x80000000u)
                                        : __uint_as_float(~k2);
  float mn = s1v + s2mv;
  mn = (mn >= 0.f) ? mn : 0.2f * mn;               // lrelu(s1 + max s2) >= row max
  float acc = 0.f, ss = 0.f;
  if (cnt > 0) {
    for (int slot = eg; slot < cnt; slot += 4) {
      int j = ei[slot];                            // LDS broadcast across 16 lanes
      float x = s1v + s2[j];
      x = (x >= 0.f) ? x : 0.2f * x;
      float p = __expf(x - mn);
      ss += p;
      acc += p * wh[j*16 + d];
    }
  } else {                                         // pathological: all columns
    for (int j = eg; j < ND; j += 4) {
      float x = s1v + s2[j];
      x = (x >= 0.f) ? x : 0.2f * x;
      float p = __expf(x - mn);
      ss += p;
      acc += p * wh[j*16 + d];
    }
  }
  acc += __shfl_xor(acc, 16); acc += __shfl_xor(acc, 32);
  ss  += __shfl_xor(ss, 16);  ss  += __shfl_xor(ss, 32);
  if (lane < 16) {
    float v = acc / ss;
    head[(size_t)row * 16 + lane] = (v > 0.f) ? v : expm1f(v);   // elu
  }
}

// ---------------- semantic attention per (g,n) (merged) ----------------
__global__ __launch_bounds__(256) void sem_kernel(const float* __restrict__ att_b,
    const float* __restrict__ att_u, float* __restrict__ ws)
{
  __shared__ float AWS[2048];
  __shared__ float AB[128], AU[128], AOM[16];
  __shared__ float hsh[2][2][16];
  __shared__ float wred[4][2];
  const int half = blockIdx.x >= 3072;
  const float* head = ws + (half ? OFF_HEADT : OFF_HEADD);
  float* pg = ws + (half ? OFF_PGT : OFF_PGD);
  float* dots = ws + (half ? OFF_DOTST : OFF_DOTSD);
  const float* aws = ws + OFF_AWS;
  const float* aom = ws + OFF_AOM;
  const int bid = half ? blockIdx.x - 3072 : blockIdx.x;
  const int t = threadIdx.x;
  for (int i = t; i < 2048; i += 256) AWS[i] = aws[i];
  if (t < 128) { AB[t] = att_b[t]; AU[t] = att_u[t]; }
  if (t < 16) AOM[t] = aom[t];
  const int grp = t >> 7, o = t & 127;
  const int gn = (bid << 1) + grp;
  const int g = gn / ND, n = gn % ND;
  if (o < 32) {
    int r = o >> 4, d = o & 15;
    hsh[grp][r][d] = head[((size_t)(g*2 + r) * ND + n) * 16 + d];
  }
  __syncthreads();
  #pragma unroll
  for (int r = 0; r < 2; ++r) {
    float a = AB[o];
    #pragma unroll
    for (int d = 0; d < 16; ++d) a += hsh[grp][r][d] * AWS[d*128 + o];
    float v = tanhf(a) * AU[o];
    #pragma unroll
    for (int off = 32; off; off >>= 1) v += __shfl_xor(v, off);
    if ((t & 63) == 0) wred[t >> 6][r] = v;
  }
  __syncthreads();
  float t0 = wred[grp*2][0] + wred[grp*2 + 1][0];
  float t1 = wred[grp*2][1] + wred[grp*2 + 1][1];
  float mx = fmaxf(t0, t1);
  float e0 = __expf(t0 - mx), e1 = __expf(t1 - mx);
  float inv = 1.f / (e0 + e1);
  float a0 = e0 * inv, a1 = e1 * inv;
  if (o < 16) {
    float pv = a0 * hsh[grp][0][o] + a1 * hsh[grp][1][o];
    pg[((size_t)g * ND + n) * 16 + o] = pv;
    float contrib = pv * AOM[o];
    #pragma unroll
    for (int off = 8; off; off >>= 1) contrib += __shfl_xor(contrib, off);
    if (o == 0) dots[(size_t)g * ND + n] = contrib;
  }
}

// ---------------- graph softmax + combine; gsum computed inline (deterministic) ----------------
__global__ __launch_bounds__(256) void finalize_kernel(float* __restrict__ ws)
{
  const int half = blockIdx.x >= 192;
  const float* pg = ws + (half ? OFF_PGT : OFF_PGD);
  const float* dots = ws + (half ? OFF_DOTST : OFF_DOTSD);
  float* f16 = ws + (half ? OFF_F16T : OFF_F16D);
  const int bid = half ? blockIdx.x - 192 : blockIdx.x;
  const int t = threadIdx.x;
  float v0 = 0.f, v1 = 0.f;
  for (int i = t; i < ND; i += 256) { v0 += dots[i]; v1 += dots[ND + i]; }
  #pragma unroll
  for (int off = 32; off; off >>= 1) { v0 += __shfl_xor(v0, off); v1 += __shfl_xor(v1, off); }
  __shared__ float red[4][2];
  if ((t & 63) == 0) { red[t >> 6][0] = v0; red[t >> 6][1] = v1; }
  __syncthreads();
  float g0 = (red[0][0] + red[1][0] + red[2][0] + red[3][0]) * (1.f/ND);
  float g1 = (red[0][1] + red[1][1] + red[2][1] + red[3][1]) * (1.f/ND);
  float mx = fmaxf(g0, g1);
  float e0 = __expf(g0 - mx), e1 = __expf(g1 - mx);
  float w0 = e0 / (e0 + e1), w1 = e1 / (e0 + e1);
  int i = bid * 256 + t;
  if (i < ND*16) f16[i] = w0 * pg[i] + w1 * pg[ND*16 + i];
}

// ---------------- decoder ----------------
__global__ __launch_bounds__(256) void dec_kernel(const int* __restrict__ ei,
    const float* __restrict__ ws, const float* __restrict__ b1,
    const float* __restrict__ w2, const float* __restrict__ b2,
    float* __restrict__ out)
{
  __shared__ float WdT[64][16], WtT[64][16];
  __shared__ float B1[64], W2s[64];
  const float* f16d = ws + OFF_F16D;
  const float* f16t = ws + OFF_F16T;
  const float* W1d = ws + OFF_W1D;
  const float* W1t = ws + OFF_W1T;
  const int t = threadIdx.x;
  for (int i = t; i < 1024; i += 256) {
    int d = i >> 6, o = i & 63;
    WdT[o][d] = W1d[i];
    WtT[o][d] = W1t[i];
  }
  if (t < 64) { B1[t] = b1[t]; W2s[t] = w2[t]; }
  __syncthreads();
  const int e = blockIdx.x * 256 + t;
  if (e >= EDG) return;
  const int i0 = ei[e], i1 = ei[EDG + e];
  const float4* pd = (const float4*)(f16d + (size_t)i0 * 16);
  const float4* pt = (const float4*)(f16t + (size_t)i1 * 16);
  float4 d0 = pd[0], d1 = pd[1], d2 = pd[2], d3 = pd[3];
  float4 e0 = pt[0], e1 = pt[1], e2 = pt[2], e3 = pt[3];
  float outv = b2[0];
  #pragma unroll 4
  for (int o = 0; o < 64; ++o) {
    const float4* wd = (const float4*)&WdT[o][0];
    const float4* wt = (const float4*)&WtT[o][0];
    float4 wd0 = wd[0], wd1 = wd[1], wd2 = wd[2], wd3 = wd[3];
    float4 wt0 = wt[0], wt1 = wt[1], wt2 = wt[2], wt3 = wt[3];
    float a = B1[o];
    a += d0.x*wd0.x + d0.y*wd0.y + d0.z*wd0.z + d0.w*wd0.w;
    a += d1.x*wd1.x + d1.y*wd1.y + d1.z*wd1.z + d1.w*wd1.w;
    a += d2.x*wd2.x + d2.y*wd2.y + d2.z*wd2.z + d2.w*wd2.w;
    a += d3.x*wd3.x + d3.y*wd3.y + d3.z*wd3.z + d3.w*wd3.w;
    a += e0.x*wt0.x + e0.y*wt0.y + e0.z*wt0.z + e0.w*wt0.w;
    a += e1.x*wt1.x + e1.y*wt1.y + e1.z*wt1.z + e1.w*wt1.w;
    a += e2.x*wt2.x + e2.y*wt2.y + e2.z*wt2.z + e2.w*wt2.w;
    a += e3.x*wt3.x + e3.y*wt3.y + e3.z*wt3.z + e3.w*wt3.w;
    a = fmaxf(a, 0.f);
    outv += a * W2s[o];
  }
  out[e] = 1.f / (1.f + __expf(-outv));
}

// ---------------- launch ----------------
extern "C" void kernel_launch(void* const* d_in, const int* in_sizes, int n_in,
                              void* d_out, int out_size, void* d_ws, size_t ws_size,
                              hipStream_t stream)
{
  const float* x_drug   = (const float*)d_in[0];
  const float* x_target = (const float*)d_in[1];
  const float* bias_d   = (const float*)d_in[2];
  const float* bias_t   = (const float*)d_in[3];
  const int*   ei       = (const int*)d_in[4];
  const float* dnn_w1 = (const float*)d_in[5];  const float* dnn_b1 = (const float*)d_in[6];
  const float* dnn_w2 = (const float*)d_in[7];  const float* dnn_b2 = (const float*)d_in[8];
  const float* dnn_w3 = (const float*)d_in[9];  const float* dnn_b3 = (const float*)d_in[10];
  const float* tnn_w1 = (const float*)d_in[11]; const float* tnn_b1 = (const float*)d_in[12];
  const float* tnn_w2 = (const float*)d_in[13]; const float* tnn_b2 = (const float*)d_in[14];
  const float* tnn_w3 = (const float*)d_in[15]; const float* tnn_b3 = (const float*)d_in[16];
  const float* gat_w  = (const float*)d_in[17];
  const float* gat_a1 = (const float*)d_in[18];
  const float* gat_a2 = (const float*)d_in[19];
  const float* att_w  = (const float*)d_in[20];
  const float* att_b  = (const float*)d_in[21];
  const float* att_u  = (const float*)d_in[22];
  const float* a_omega= (const float*)d_in[23];
  const float* dec_w1 = (const float*)d_in[24]; const float* dec_b1 = (const float*)d_in[25];
  const float* dec_w2 = (const float*)d_in[26]; const float* dec_b2 = (const float*)d_in[27];
  float* out = (float*)d_out;
  float* ws = (float*)d_ws;

  ushort* w1dh = (ushort*)(ws + OFF_W1DH); ushort* w1dl = (ushort*)(ws + OFF_W1DL);
  ushort* w1th = (ushort*)(ws + OFF_W1TH); ushort* w1tl = (ushort*)(ws + OFF_W1TL);
  ushort* w2dh = (ushort*)(ws + OFF_W2DH); ushort* w2dl = (ushort*)(ws + OFF_W2DL);
  ushort* w2th = (ushort*)(ws + OFF_W2TH); ushort* w2tl = (ushort*)(ws + OFF_W2TL);
  ushort* w3dh = (ushort*)(ws + OFF_W3DH); ushort* w3dl = (ushort*)(ws + OFF_W3DL);
  ushort* w3th = (ushort*)(ws + OFF_W3TH); ushort* w3tl = (ushort*)(ws + OFF_W3TL);
  ushort* xdh  = (ushort*)(ws + OFF_XDH);  ushort* xdl  = (ushort*)(ws + OFF_XDL);
  ushort* xth  = (ushort*)(ws + OFF_XTH);  ushort* xtl  = (ushort*)(ws + OFF_XTL);
  ushort* h1dh = (ushort*)(ws + OFF_H1DH); ushort* h1dl = (ushort*)(ws + OFF_H1DL);
  ushort* h1th = (ushort*)(ws + OFF_H1TH); ushort* h1tl = (ushort*)(ws + OFF_H1TL);
  ushort* h2dh = (ushort*)(ws + OFF_H2DH); ushort* h2dl = (ushort*)(ws + OFF_H2DL);
  ushort* h2th = (ushort*)(ws + OFF_H2TH); ushort* h2tl = (ushort*)(ws + OFF_H2TL);
  float* featD = ws + OFF_FEATD;
  float* featT = ws + OFF_FEATT;

  prep_all<<<7650, 256, 0, stream>>>(dnn_w1, tnn_w1, dnn_w2, tnn_w2, dnn_w3, tnn_w3,
      x_drug, x_target, att_w, dec_w1, a_omega, ws);

  // L1: drug K=1024, target K=1280 (N=512), BM=128 -> grid (8,48)=384 blocks
  mfma_gemm2<128,1><<<dim3(8,48), 256, 0, stream>>>(
      xdh, xdl, w1dh, w1dl, dnn_b1, nullptr, h1dh, h1dl,
      xth, xtl, w1th, w1tl, tnn_b1, nullptr, h1th, h1tl, 512, 1024, 1280);
  // L2: K=512, N=256, BM=64 -> grid (4,96)=384 blocks
  mfma_gemm2<64,1><<<dim3(4,96), 256, 0, stream>>>(
      h1dh, h1dl, w2dh, w2dl, dnn_b2, nullptr, h2dh, h2dl,
      h1th, h1tl, w2th, w2tl, tnn_b2, nullptr, h2th, h2tl, 256, 512, 512);
  // L3: K=256, N=128, BM=64 -> grid (2,96)=192 blocks, f32 out
  mfma_gemm2<64,0><<<dim3(2,96), 256, 0, stream>>>(
      h2dh, h2dl, w3dh, w3dl, dnn_b3, featD, nullptr, nullptr,
      h2th, h2tl, w3th, w3tl, tnn_b3, featT, nullptr, nullptr, 128, 256, 256);

  wh_kernel<<<384, 256, 0, stream>>>(featD, featT, gat_w, gat_a1, gat_a2, ws);

  scanacc_kernel<<<6144, 256, 0, stream>>>(bias_d, bias_t, ws);

  sem_kernel<<<6144, 256, 0, stream>>>(att_b, att_u, ws);
  finalize_kernel<<<384, 256, 0, stream>>>(ws);

  dec_kernel<<<(EDG + 255) / 256, 256, 0, stream>>>(ei, ws, dec_b1, dec_w2, dec_b2, out);
}

// Round 13
// 204.359 us; speedup vs baseline: 1.1005x; 1.0372x over previous
//
#include <hip/hip_runtime.h>
#include <math.h>

#define ND 3072
#define EDG 100000
#define MAXE 128
#define BSL (64*8 + 16)    // padded B k-slab stride (ushorts)

typedef __attribute__((ext_vector_type(8))) short short8;
typedef __attribute__((ext_vector_type(4))) float f32x4;

// ---------------- workspace layout (float offsets) ----------------
enum : size_t {
  OFF_FEATD = 0,                         // 3072*128
  OFF_FEATT = OFF_FEATD + 393216,
  OFF_WHD   = OFF_FEATT + 393216,        // 3072*16
  OFF_WHT   = OFF_WHD + 49152,
  OFF_S1D   = OFF_WHT + 49152,
  OFF_S2D   = OFF_S1D + 3072,
  OFF_S1T   = OFF_S2D + 3072,
  OFF_S2T   = OFF_S1T + 3072,
  OFF_PGD   = OFF_S2T + 3072,            // [2,3072,16]
  OFF_PGT   = OFF_PGD + 98304,
  OFF_F16D  = OFF_PGT + 98304,           // [3072,16]
  OFF_F16T  = OFF_F16D + 49152,
  OFF_AWS   = OFF_F16T + 49152,          // [16][128]
  OFF_W1D   = OFF_AWS + 2048,            // [16][64]
  OFF_W1T   = OFF_W1D + 1024,
  OFF_AOM   = OFF_W1T + 1024,            // [16]
  OFF_DOTSD = OFF_AOM + 16,              // [2][3072]
  OFF_DOTST = OFF_DOTSD + 6144,
  OFF_S2MD  = OFF_DOTST + 6144,          // uint-encoded max slots
  OFF_S2MT  = OFF_S2MD + 1,
  // weight splits [K/8][N][8] bf16 hi/lo
  OFF_W1DH  = ((OFF_S2MT + 4) & ~(size_t)3),
  OFF_W1DL  = OFF_W1DH + 262144,
  OFF_W1TH  = OFF_W1DL + 262144,
  OFF_W1TL  = OFF_W1TH + 327680,
  OFF_W2DH  = OFF_W1TL + 327680,
  OFF_W2DL  = OFF_W2DH + 65536,
  OFF_W2TH  = OFF_W2DL + 65536,
  OFF_W2TL  = OFF_W2TH + 65536,
  OFF_W3DH  = OFF_W2TL + 65536,
  OFF_W3DL  = OFF_W3DH + 16384,
  OFF_W3TH  = OFF_W3DL + 16384,
  OFF_W3TL  = OFF_W3TH + 16384,
  // input splits, row-major bf16 hi/lo
  OFF_XDH   = OFF_W3TL + 16384,
  OFF_XDL   = OFF_XDH + 1572864,
  OFF_XTH   = OFF_XDL + 1572864,
  OFF_XTL   = OFF_XTH + 1966080,
  // activation splits (row-major bf16 hi/lo)
  OFF_H1DH  = OFF_XTL + 1966080,
  OFF_H1DL  = OFF_H1DH + 786432,
  OFF_H1TH  = OFF_H1DL + 786432,
  OFF_H1TL  = OFF_H1TH + 786432,
  OFF_H2DH  = OFF_H1TL + 786432,
  OFF_H2DL  = OFF_H2DH + 393216,
  OFF_H2TH  = OFF_H2DL + 393216,
  OFF_H2TL  = OFF_H2TH + 393216,
  WS_GRAND  = OFF_H2TL + 393216
};

// ---------------- bf16 split helpers ----------------
__device__ __forceinline__ ushort f2bf(float f) {
  union { float f; unsigned u; } v; v.f = f;
  unsigned r = (v.u + 0x7fffu + ((v.u >> 16) & 1u)) >> 16;
  return (ushort)r;
}
__device__ __forceinline__ float bf2f(ushort h) {
  union { float f; unsigned u; } v; v.u = ((unsigned)h) << 16;
  return v.f;
}

// ---------------- mega prep: weight splits + input splits + small folds ----------------
__global__ __launch_bounds__(256) void prep_all(
    const float* __restrict__ w1d, const float* __restrict__ w1t,
    const float* __restrict__ w2d, const float* __restrict__ w2t,
    const float* __restrict__ w3d, const float* __restrict__ w3t,
    const float* __restrict__ xd,  const float* __restrict__ xt,
    const float* __restrict__ att_w, const float* __restrict__ dec_w1,
    const float* __restrict__ a_omega, float* __restrict__ ws)
{
  const int b = blockIdx.x, t = threadIdx.x;
  if (b < 736) {                         // [K][N] f32 -> [K/8][N][8] bf16 hi/lo
    const float* W; ushort* hi; ushort* lo; int nsh, base;
    if (b < 256)      { W=w1d; hi=(ushort*)(ws+OFF_W1DH); lo=(ushort*)(ws+OFF_W1DL); nsh=9; base=0; }
    else if (b < 576) { W=w1t; hi=(ushort*)(ws+OFF_W1TH); lo=(ushort*)(ws+OFF_W1TL); nsh=9; base=256; }
    else if (b < 640) { W=w2d; hi=(ushort*)(ws+OFF_W2DH); lo=(ushort*)(ws+OFF_W2DL); nsh=8; base=576; }
    else if (b < 704) { W=w2t; hi=(ushort*)(ws+OFF_W2TH); lo=(ushort*)(ws+OFF_W2TL); nsh=8; base=640; }
    else if (b < 720) { W=w3d; hi=(ushort*)(ws+OFF_W3DH); lo=(ushort*)(ws+OFF_W3DL); nsh=7; base=704; }
    else              { W=w3t; hi=(ushort*)(ws+OFF_W3TH); lo=(ushort*)(ws+OFF_W3TL); nsh=7; base=720; }
    const int u = (b - base)*256 + t;
    const int k8 = u >> nsh;
    const int n  = u & ((1 << nsh) - 1);
    __align__(16) ushort h8[8], l8[8];
    #pragma unroll
    for (int j2 = 0; j2 < 8; ++j2) {
      float x = W[(size_t)(k8*8 + j2) * (1 << nsh) + n];
      ushort h = f2bf(x);
      h8[j2] = h; l8[j2] = f2bf(x - bf2f(h));
    }
    *(uint4*)&hi[(size_t)u*8] = *(const uint4*)h8;
    *(uint4*)&lo[(size_t)u*8] = *(const uint4*)l8;
  } else if (b < 7648) {                 // row-major f32 -> row-major bf16 hi/lo
    const float* X; ushort* hi; ushort* lo; int base;
    if (b < 3808) { X=xd; hi=(ushort*)(ws+OFF_XDH); lo=(ushort*)(ws+OFF_XDL); base=736; }
    else          { X=xt; hi=(ushort*)(ws+OFF_XTH); lo=(ushort*)(ws+OFF_XTL); base=3808; }
    const size_t u = ((size_t)(b-base)*256 + t)*4;
    float4 v = *(const float4*)&X[u];
    ushort4 h, l;
    h.x=f2bf(v.x); l.x=f2bf(v.x-bf2f(h.x));
    h.y=f2bf(v.y); l.y=f2bf(v.y-bf2f(h.y));
    h.z=f2bf(v.z); l.z=f2bf(v.z-bf2f(h.z));
    h.w=f2bf(v.w); l.w=f2bf(v.w-bf2f(h.w));
    *(ushort4*)&hi[u] = h; *(ushort4*)&lo[u] = l;
  } else if (b == 7648) {                // aws + aom folds + s2max init
    float* aws = ws + OFF_AWS; float* aom = ws + OFF_AOM;
    for (int i = t; i < 2048; i += 256) {
      int d = i >> 7, o = i & 127;
      float sum = 0.f;
      #pragma unroll
      for (int tt = 0; tt < 8; ++tt) sum += att_w[(tt*16 + d)*128 + o];
      aws[i] = sum;
    }
    if (t < 16) {
      float sum = 0.f;
      #pragma unroll
      for (int tt = 0; tt < 8; ++tt) sum += a_omega[tt*16 + t];
      aom[t] = sum;
    }
    if (t == 0) {
      ((unsigned*)(ws + OFF_S2MD))[0] = 0u;   // encodes "most negative"
      ((unsigned*)(ws + OFF_S2MT))[0] = 0u;
    }
  } else {                               // dec_w1 folds
    float* W1d = ws + OFF_W1D; float* W1t = ws + OFF_W1T;
    for (int i = t; i < 1024; i += 256) {
      int d = i >> 6, o = i & 63;
      float sd = 0.f, st = 0.f;
      #pragma unroll
      for (int tt = 0; tt < 8; ++tt) {
        sd += dec_w1[(tt*16 + d)*64 + o];
        st += dec_w1[(128 + tt*16 + d)*64 + o];
      }
      W1d[i] = sd; W1t[i] = st;
    }
  }
}

// ---------------- split-bf16 MFMA GEMM, merged drug+target, BM-templated ----------------
template<int BM, int EPI>
__global__ __launch_bounds__(256) void mfma_gemm2(
    const ushort* __restrict__ A0h, const ushort* __restrict__ A0l,
    const ushort* __restrict__ B0h, const ushort* __restrict__ B0l,
    const float* __restrict__ b0, float* __restrict__ C0f,
    ushort* __restrict__ C0h, ushort* __restrict__ C0l,
    const ushort* __restrict__ A1h, const ushort* __restrict__ A1l,
    const ushort* __restrict__ B1h, const ushort* __restrict__ B1l,
    const float* __restrict__ b1, float* __restrict__ C1f,
    ushort* __restrict__ C1h, ushort* __restrict__ C1l,
    int N, int K0, int K1)
{
  constexpr int ASLT = BM*8 + 16;        // padded A k-slab stride
  constexpr int NP   = 3072 / BM;        // row panels per half
  constexpr int AI   = BM / 32;          // per-thread A staging units (4 or 2)
  __shared__ __align__(16) ushort Ah[8*ASLT], Al[8*ASLT];
  __shared__ __align__(16) ushort Bh[8*BSL], Bl[8*BSL];
  const int t = threadIdx.x;
  const int lane = t & 63, w = t >> 6;
  const int wr = w >> 1, wc = w & 1;
  const int l15 = lane & 15, l4 = lane >> 4;

  // XCD-aware swizzle (total grid divisible by 8)
  const int id = blockIdx.y * gridDim.x + blockIdx.x;
  const int xcd = id & 7;
  const int j = id >> 3;
  const int bx = j % gridDim.x;
  const int by = (j / gridDim.x) * 8 + xcd;
  const int half = by >= NP;
  const int row0 = (half ? by - NP : by) * BM;
  const int col0 = bx << 6;
  const ushort* Ahi = half ? A1h : A0h; const ushort* Alo = half ? A1l : A0l;
  const ushort* Bhi = half ? B1h : B0h; const ushort* Blo = half ? B1l : B0l;
  const float* bias = half ? b1 : b0;
  float* Cf = half ? C1f : C0f;
  ushort* Chi = half ? C1h : C0h; ushort* Clo = half ? C1l : C0l;
  const int K = half ? K1 : K0;

  f32x4 acc[AI][2] = {};

  const int arow = t >> 3;        // 0..31
  const int akc  = t & 7;         // k-chunk 0..7
  const int bkc  = t >> 6;        // 0..3
  const int bcol = t & 63;

  uint4 sa0, sa1, sa2, sa3, sl0, sl1, sl2, sl3, sb0, sb1, sc0, sc1;

#define GLOAD(k0_) { \
    size_t g0 = (size_t)(row0 + arow) * K + (k0_) + (akc << 3); \
    sa0 = *(const uint4*)(Ahi + g0);                     sl0 = *(const uint4*)(Alo + g0); \
    sa1 = *(const uint4*)(Ahi + g0 + 32*(size_t)K);      sl1 = *(const uint4*)(Alo + g0 + 32*(size_t)K); \
    if (AI > 2) { \
      sa2 = *(const uint4*)(Ahi + g0 + 64*(size_t)K);    sl2 = *(const uint4*)(Alo + g0 + 64*(size_t)K); \
      sa3 = *(const uint4*)(Ahi + g0 + 96*(size_t)K);    sl3 = *(const uint4*)(Alo + g0 + 96*(size_t)K); \
    } \
    size_t gb0 = ((size_t)(((k0_) >> 3) + bkc    ) * N + col0 + bcol) << 3; \
    size_t gb1 = ((size_t)(((k0_) >> 3) + bkc + 4) * N + col0 + bcol) << 3; \
    sb0 = *(const uint4*)(Bhi + gb0); sc0 = *(const uint4*)(Blo + gb0); \
    sb1 = *(const uint4*)(Bhi + gb1); sc1 = *(const uint4*)(Blo + gb1); \
  }

#define LDSW() { \
    int ao = akc * ASLT + arow * 8; \
    *(uint4*)&Ah[ao      ] = sa0;  *(uint4*)&Al[ao      ] = sl0; \
    *(uint4*)&Ah[ao + 256] = sa1;  *(uint4*)&Al[ao + 256] = sl1; \
    if (AI > 2) { \
      *(uint4*)&Ah[ao + 512] = sa2;  *(uint4*)&Al[ao + 512] = sl2; \
      *(uint4*)&Ah[ao + 768] = sa3;  *(uint4*)&Al[ao + 768] = sl3; \
    } \
    int bo = bkc * BSL + bcol * 8; \
    *(uint4*)&Bh[bo        ] = sb0; *(uint4*)&Bl[bo        ] = sc0; \
    *(uint4*)&Bh[bo + 4*BSL] = sb1; *(uint4*)&Bl[bo + 4*BSL] = sc1; \
  }

  GLOAD(0);
  for (int k0 = 0; k0 < K; k0 += 64) {
    __syncthreads();
    LDSW();
    __syncthreads();
    if (k0 + 64 < K) GLOAD(k0 + 64);     // prefetch into named regs, flies under MFMA
    #pragma unroll
    for (int ks = 0; ks < 2; ++ks) {
      const int kch = (ks << 2) + l4;
      const int bbase = kch * BSL + ((wc << 5) + l15) * 8;
      short8 fb0 = *(const short8*)&Bh[bbase];
      short8 fb1 = *(const short8*)&Bh[bbase + 128];
      short8 gl0 = *(const short8*)&Bl[bbase];
      short8 gl1 = *(const short8*)&Bl[bbase + 128];
      #pragma unroll
      for (int m = 0; m < AI; ++m) {
        const int abase = kch * ASLT + (wr*(BM/2) + (m << 4) + l15) * 8;
        short8 fa = *(const short8*)&Ah[abase];
        short8 fl = *(const short8*)&Al[abase];
        acc[m][0] = __builtin_amdgcn_mfma_f32_16x16x32_bf16(fa, fb0, acc[m][0], 0, 0, 0);
        acc[m][0] = __builtin_amdgcn_mfma_f32_16x16x32_bf16(fa, gl0, acc[m][0], 0, 0, 0);
        acc[m][0] = __builtin_amdgcn_mfma_f32_16x16x32_bf16(fl, fb0, acc[m][0], 0, 0, 0);
        acc[m][1] = __builtin_amdgcn_mfma_f32_16x16x32_bf16(fa, fb1, acc[m][1], 0, 0, 0);
        acc[m][1] = __builtin_amdgcn_mfma_f32_16x16x32_bf16(fa, gl1, acc[m][1], 0, 0, 0);
        acc[m][1] = __builtin_amdgcn_mfma_f32_16x16x32_bf16(fl, fb1, acc[m][1], 0, 0, 0);
      }
    }
  }
#undef GLOAD
#undef LDSW

  // ---- epilogue: bias + relu; C/D layout col=lane&15, row=(lane>>4)*4+reg ----
  #pragma unroll
  for (int n = 0; n < 2; ++n) {
    int col = col0 + (wc << 5) + (n << 4) + l15;
    float bb = bias[col];
    #pragma unroll
    for (int m = 0; m < AI; ++m) {
      int rowb = row0 + wr*(BM/2) + (m << 4) + (l4 << 2);
      #pragma unroll
      for (int r = 0; r < 4; ++r) {
        float v = fmaxf(acc[m][n][r] + bb, 0.f);
        size_t d = (size_t)(rowb + r) * N + col;
        if (EPI == 0) {
          Cf[d] = v;
        } else {
          ushort h = f2bf(v);
          Chi[d] = h;
          Clo[d] = f2bf(v - bf2f(h));
        }
      }
    }
  }
}

// ---------------- wh = feats@gat_w; s1, s2; + deterministic global max(s2) ----------------
__global__ __launch_bounds__(256) void wh_kernel(const float* __restrict__ featD,
    const float* __restrict__ featT,
    const float* __restrict__ gw, const float* __restrict__ ga1, const float* __restrict__ ga2,
    float* __restrict__ ws)
{
  __shared__ float W[128*16];
  __shared__ float A1[16], A2[16];
  const int t = threadIdx.x;
  const int half = blockIdx.x >= 192;
  const float* feat = half ? featT : featD;
  float* wh = ws + (half ? OFF_WHT : OFF_WHD);
  float* s1 = ws + (half ? OFF_S1T : OFF_S1D);
  float* s2 = ws + (half ? OFF_S2T : OFF_S2D);
  unsigned* s2m = (unsigned*)(ws + (half ? OFF_S2MT : OFF_S2MD));
  const int bid = half ? blockIdx.x - 192 : blockIdx.x;
  for (int i = t; i < 2048; i += 256) W[i] = gw[i];
  if (t < 16) { A1[t] = ga1[t]; A2[t] = ga2[t]; }
  __syncthreads();
  const int n = (bid << 4) + (t >> 4);
  const int d = t & 15;
  const float* f = feat + (size_t)n * 128;
  float acc = 0.f;
  #pragma unroll 8
  for (int k = 0; k < 128; ++k) acc += f[k] * W[k*16 + d];
  wh[(size_t)n*16 + d] = acc;
  float v1 = acc * A1[d], v2 = acc * A2[d];
  #pragma unroll
  for (int off = 8; off; off >>= 1) { v1 += __shfl_xor(v1, off); v2 += __shfl_xor(v2, off); }
  if (d == 0) {
    s1[n] = v1; s2[n] = v2;
    unsigned u = __float_as_uint(v2);
    unsigned key = (u & 0x80000000u) ? ~u : (u | 0x80000000u);  // monotone encoding
    atomicMax(s2m, key);                                        // max: order-independent
  }
}

// ---------------- fused: bias scan -> LDS compaction -> softmax gather -> semantic attention ----------------
// block covers (half, g, n0, n0+1): waves (r,dn) handle rows (g*2+r)*ND + n0+dn.
__global__ __launch_bounds__(256) void scanacc_sem(const float* __restrict__ bias_d,
    const float* __restrict__ bias_t, const float* __restrict__ att_b,
    const float* __restrict__ att_u, float* __restrict__ ws)
{
  __shared__ ushort eidx[4][MAXE];
  __shared__ float AWS[2048];
  __shared__ float AB[128], AU[128], AOM[16];
  __shared__ float hsh[2][2][16];      // [dn][r][d]
  __shared__ float wred[4][2];
  const int t = threadIdx.x;
  // stage semantic-attention tables (consumed after the barrier below)
  for (int i = t; i < 2048; i += 256) AWS[i] = (ws + OFF_AWS)[i];
  if (t < 128) { AB[t] = att_b[t]; AU[t] = att_u[t]; }
  if (t < 16) AOM[t] = (ws + OFF_AOM)[t];

  const int half = blockIdx.x >= 3072;
  const float* bias = half ? bias_t : bias_d;
  const float* s1 = ws + (half ? OFF_S1T : OFF_S1D);
  const float* s2 = ws + (half ? OFF_S2T : OFF_S2D);
  const unsigned* s2mp = (const unsigned*)(ws + (half ? OFF_S2MT : OFF_S2MD));
  const float* wh = ws + (half ? OFF_WHT : OFF_WHD);
  float* pg = ws + (half ? OFF_PGT : OFF_PGD);
  float* dots = ws + (half ? OFF_DOTST : OFF_DOTSD);
  const int b2 = half ? blockIdx.x - 3072 : blockIdx.x;   // 0..3071
  const int g = b2 / 1536;
  const int n0 = (b2 % 1536) << 1;
  const int lane = t & 63;
  const int wv = t >> 6;
  const int r = wv >> 1, dn = wv & 1;
  const int n = n0 + dn;
  const int row = (g*2 + r) * ND + n;
  const f32x4* brow = (const f32x4*)(bias + (size_t)row * ND);
  ushort* ei = &eidx[wv][0];
  const unsigned long long ltmask = (1ull << lane) - 1ull;

  // ---- phase A: compact edge column indices into LDS (wave-local, no barrier) ----
  int cnt = 0;
  #pragma unroll 3
  for (int i = 0; i < ND/256; ++i) {
    const int j4 = lane + (i << 6);
    f32x4 b = __builtin_nontemporal_load(&brow[j4]);
    #pragma unroll
    for (int c = 0; c < 4; ++c) {
      bool e = b[c] > -1e8f;
      unsigned long long mask = __ballot(e);
      if (e) {
        int pos = cnt + __popcll(mask & ltmask);
        if (pos < MAXE) ei[pos] = (unsigned short)((j4 << 2) + c);
      }
      cnt += __popcll(mask);             // wave-uniform
    }
  }
  if (cnt > MAXE) cnt = MAXE;

  // ---- phase B: dense softmax-weighted aggregation from LDS list ----
  const int eg = lane >> 4, d = lane & 15;
  const float s1v = s1[n];
  const unsigned k2 = *s2mp;
  const float s2mv = (k2 & 0x80000000u) ? __uint_as_float(k2 ^ 0x80000000u)
                                        : __uint_as_float(~k2);
  float mn = s1v + s2mv;
  mn = (mn >= 0.f) ? mn : 0.2f * mn;     // lrelu(s1 + max s2) >= row max
  float acc = 0.f, ss = 0.f;
  if (cnt > 0) {
    for (int slot = eg; slot < cnt; slot += 4) {
      int j = ei[slot];
      float x = s1v + s2[j];
      x = (x >= 0.f) ? x : 0.2f * x;
      float p = __expf(x - mn);
      ss += p;
      acc += p * wh[j*16 + d];
    }
  } else {                               // pathological: all columns
    for (int j = eg; j < ND; j += 4) {
      float x = s1v + s2[j];
      x = (x >= 0.f) ? x : 0.2f * x;
      float p = __expf(x - mn);
      ss += p;
      acc += p * wh[j*16 + d];
    }
  }
  acc += __shfl_xor(acc, 16); acc += __shfl_xor(acc, 32);
  ss  += __shfl_xor(ss, 16);  ss  += __shfl_xor(ss, 32);
  if (lane < 16) {
    float v = acc / ss;
    hsh[dn][r][lane] = (v > 0.f) ? v : expm1f(v);   // elu -> head in LDS
  }
  __syncthreads();

  // ---- phase C: semantic attention per (g, n0+grp) ----
  const int grp = t >> 7, o = t & 127;
  const int nn = n0 + grp;
  #pragma unroll
  for (int rr = 0; rr < 2; ++rr) {
    float a = AB[o];
    #pragma unroll
    for (int dd = 0; dd < 16; ++dd) a += hsh[grp][rr][dd] * AWS[dd*128 + o];
    float v = tanhf(a) * AU[o];
    #pragma unroll
    for (int off = 32; off; off >>= 1) v += __shfl_xor(v, off);
    if ((t & 63) == 0) wred[t >> 6][rr] = v;
  }
  __syncthreads();
  float t0 = wred[grp*2][0] + wred[grp*2 + 1][0];
  float t1 = wred[grp*2][1] + wred[grp*2 + 1][1];
  float mx = fmaxf(t0, t1);
  float e0 = __expf(t0 - mx), e1 = __expf(t1 - mx);
  float inv = 1.f / (e0 + e1);
  float a0 = e0 * inv, a1 = e1 * inv;
  if (o < 16) {
    float pv = a0 * hsh[grp][0][o] + a1 * hsh[grp][1][o];
    pg[((size_t)g * ND + nn) * 16 + o] = pv;
    float contrib = pv * AOM[o];
    #pragma unroll
    for (int off = 8; off; off >>= 1) contrib += __shfl_xor(contrib, off);
    if (o == 0) dots[(size_t)g * ND + nn] = contrib;
  }
}

// ---------------- graph softmax + combine; gsum computed inline (deterministic) ----------------
__global__ __launch_bounds__(256) void finalize_kernel(float* __restrict__ ws)
{
  const int half = blockIdx.x >= 192;
  const float* pg = ws + (half ? OFF_PGT : OFF_PGD);
  const float* dots = ws + (half ? OFF_DOTST : OFF_DOTSD);
  float* f16 = ws + (half ? OFF_F16T : OFF_F16D);
  const int bid = half ? blockIdx.x - 192 : blockIdx.x;
  const int t = threadIdx.x;
  float v0 = 0.f, v1 = 0.f;
  for (int i = t; i < ND; i += 256) { v0 += dots[i]; v1 += dots[ND + i]; }
  #pragma unroll
  for (int off = 32; off; off >>= 1) { v0 += __shfl_xor(v0, off); v1 += __shfl_xor(v1, off); }
  __shared__ float red[4][2];
  if ((t & 63) == 0) { red[t >> 6][0] = v0; red[t >> 6][1] = v1; }
  __syncthreads();
  float g0 = (red[0][0] + red[1][0] + red[2][0] + red[3][0]) * (1.f/ND);
  float g1 = (red[0][1] + red[1][1] + red[2][1] + red[3][1]) * (1.f/ND);
  float mx = fmaxf(g0, g1);
  float e0 = __expf(g0 - mx), e1 = __expf(g1 - mx);
  float w0 = e0 / (e0 + e1), w1 = e1 / (e0 + e1);
  int i = bid * 256 + t;
  if (i < ND*16) f16[i] = w0 * pg[i] + w1 * pg[ND*16 + i];
}

// ---------------- decoder ----------------
__global__ __launch_bounds__(256) void dec_kernel(const int* __restrict__ ei,
    const float* __restrict__ ws, const float* __restrict__ b1,
    const float* __restrict__ w2, const float* __restrict__ b2,
    float* __restrict__ out)
{
  __shared__ float WdT[64][16], WtT[64][16];
  __shared__ float B1[64], W2s[64];
  const float* f16d = ws + OFF_F16D;
  const float* f16t = ws + OFF_F16T;
  const float* W1d = ws + OFF_W1D;
  const float* W1t = ws + OFF_W1T;
  const int t = threadIdx.x;
  for (int i = t; i < 1024; i += 256) {
    int d = i >> 6, o = i & 63;
    WdT[o][d] = W1d[i];
    WtT[o][d] = W1t[i];
  }
  if (t < 64) { B1[t] = b1[t]; W2s[t] = w2[t]; }
  __syncthreads();
  const int e = blockIdx.x * 256 + t;
  if (e >= EDG) return;
  const int i0 = ei[e], i1 = ei[EDG + e];
  const float4* pd = (const float4*)(f16d + (size_t)i0 * 16);
  const float4* pt = (const float4*)(f16t + (size_t)i1 * 16);
  float4 d0 = pd[0], d1 = pd[1], d2 = pd[2], d3 = pd[3];
  float4 e0 = pt[0], e1 = pt[1], e2 = pt[2], e3 = pt[3];
  float outv = b2[0];
  #pragma unroll 4
  for (int o = 0; o < 64; ++o) {
    const float4* wd = (const float4*)&WdT[o][0];
    const float4* wt = (const float4*)&WtT[o][0];
    float4 wd0 = wd[0], wd1 = wd[1], wd2 = wd[2], wd3 = wd[3];
    float4 wt0 = wt[0], wt1 = wt[1], wt2 = wt[2], wt3 = wt[3];
    float a = B1[o];
    a += d0.x*wd0.x + d0.y*wd0.y + d0.z*wd0.z + d0.w*wd0.w;
    a += d1.x*wd1.x + d1.y*wd1.y + d1.z*wd1.z + d1.w*wd1.w;
    a += d2.x*wd2.x + d2.y*wd2.y + d2.z*wd2.z + d2.w*wd2.w;
    a += d3.x*wd3.x + d3.y*wd3.y + d3.z*wd3.z + d3.w*wd3.w;
    a += e0.x*wt0.x + e0.y*wt0.y + e0.z*wt0.z + e0.w*wt0.w;
    a += e1.x*wt1.x + e1.y*wt1.y + e1.z*wt1.z + e1.w*wt1.w;
    a += e2.x*wt2.x + e2.y*wt2.y + e2.z*wt2.z + e2.w*wt2.w;
    a += e3.x*wt3.x + e3.y*wt3.y + e3.z*wt3.z + e3.w*wt3.w;
    a = fmaxf(a, 0.f);
    outv += a * W2s[o];
  }
  out[e] = 1.f / (1.f + __expf(-outv));
}

// ---------------- launch ----------------
extern "C" void kernel_launch(void* const* d_in, const int* in_sizes, int n_in,
                              void* d_out, int out_size, void* d_ws, size_t ws_size,
                              hipStream_t stream)
{
  const float* x_drug   = (const float*)d_in[0];
  const float* x_target = (const float*)d_in[1];
  const float* bias_d   = (const float*)d_in[2];
  const float* bias_t   = (const float*)d_in[3];
  const int*   ei       = (const int*)d_in[4];
  const float* dnn_w1 = (const float*)d_in[5];  const float* dnn_b1 = (const float*)d_in[6];
  const float* dnn_w2 = (const float*)d_in[7];  const float* dnn_b2 = (const float*)d_in[8];
  const float* dnn_w3 = (const float*)d_in[9];  const float* dnn_b3 = (const float*)d_in[10];
  const float* tnn_w1 = (const float*)d_in[11]; const float* tnn_b1 = (const float*)d_in[12];
  const float* tnn_w2 = (const float*)d_in[13]; const float* tnn_b2 = (const float*)d_in[14];
  const float* tnn_w3 = (const float*)d_in[15]; const float* tnn_b3 = (const float*)d_in[16];
  const float* gat_w  = (const float*)d_in[17];
  const float* gat_a1 = (const float*)d_in[18];
  const float* gat_a2 = (const float*)d_in[19];
  const float* att_w  = (const float*)d_in[20];
  const float* att_b  = (const float*)d_in[21];
  const float* att_u  = (const float*)d_in[22];
  const float* a_omega= (const float*)d_in[23];
  const float* dec_w1 = (const float*)d_in[24]; const float* dec_b1 = (const float*)d_in[25];
  const float* dec_w2 = (const float*)d_in[26]; const float* dec_b2 = (const float*)d_in[27];
  float* out = (float*)d_out;
  float* ws = (float*)d_ws;

  ushort* w1dh = (ushort*)(ws + OFF_W1DH); ushort* w1dl = (ushort*)(ws + OFF_W1DL);
  ushort* w1th = (ushort*)(ws + OFF_W1TH); ushort* w1tl = (ushort*)(ws + OFF_W1TL);
  ushort* w2dh = (ushort*)(ws + OFF_W2DH); ushort* w2dl = (ushort*)(ws + OFF_W2DL);
  ushort* w2th = (ushort*)(ws + OFF_W2TH); ushort* w2tl = (ushort*)(ws + OFF_W2TL);
  ushort* w3dh = (ushort*)(ws + OFF_W3DH); ushort* w3dl = (ushort*)(ws + OFF_W3DL);
  ushort* w3th = (ushort*)(ws + OFF_W3TH); ushort* w3tl = (ushort*)(ws + OFF_W3TL);
  ushort* xdh  = (ushort*)(ws + OFF_XDH);  ushort* xdl  = (ushort*)(ws + OFF_XDL);
  ushort* xth  = (ushort*)(ws + OFF_XTH);  ushort* xtl  = (ushort*)(ws + OFF_XTL);
  ushort* h1dh = (ushort*)(ws + OFF_H1DH); ushort* h1dl = (ushort*)(ws + OFF_H1DL);
  ushort* h1th = (ushort*)(ws + OFF_H1TH); ushort* h1tl = (ushort*)(ws + OFF_H1TL);
  ushort* h2dh = (ushort*)(ws + OFF_H2DH); ushort* h2dl = (ushort*)(ws + OFF_H2DL);
  ushort* h2th = (ushort*)(ws + OFF_H2TH); ushort* h2tl = (ushort*)(ws + OFF_H2TL);
  float* featD = ws + OFF_FEATD;
  float* featT = ws + OFF_FEATT;

  prep_all<<<7650, 256, 0, stream>>>(dnn_w1, tnn_w1, dnn_w2, tnn_w2, dnn_w3, tnn_w3,
      x_drug, x_target, att_w, dec_w1, a_omega, ws);

  // L1: drug K=1024, target K=1280 (N=512), BM=128 -> grid (8,48)=384 blocks
  mfma_gemm2<128,1><<<dim3(8,48), 256, 0, stream>>>(
      xdh, xdl, w1dh, w1dl, dnn_b1, nullptr, h1dh, h1dl,
      xth, xtl, w1th, w1tl, tnn_b1, nullptr, h1th, h1tl, 512, 1024, 1280);
  // L2: K=512, N=256, BM=64 -> grid (4,96)=384 blocks
  mfma_gemm2<64,1><<<dim3(4,96), 256, 0, stream>>>(
      h1dh, h1dl, w2dh, w2dl, dnn_b2, nullptr, h2dh, h2dl,
      h1th, h1tl, w2th, w2tl, tnn_b2, nullptr, h2th, h2tl, 256, 512, 512);
  // L3: K=256, N=128, BM=64 -> grid (2,96)=192 blocks, f32 out
  mfma_gemm2<64,0><<<dim3(2,96), 256, 0, stream>>>(
      h2dh, h2dl, w3dh, w3dl, dnn_b3, featD, nullptr, nullptr,
      h2th, h2tl, w3th, w3tl, tnn_b3, featT, nullptr, nullptr, 128, 256, 256);

  wh_kernel<<<384, 256, 0, stream>>>(featD, featT, gat_w, gat_a1, gat_a2, ws);

  scanacc_sem<<<6144, 256, 0, stream>>>(bias_d, bias_t, att_b, att_u, ws);

  finalize_kernel<<<384, 256, 0, stream>>>(ws);

  dec_kernel<<<(EDG + 255) / 256, 256, 0, stream>>>(ei, ws, dec_b1, dec_w2, dec_b2, out);
}